// Round 2
// baseline (2508.210 us; speedup 1.0000x reference)
//
#include <hip/hip_runtime.h>
#include <math.h>

#define BB 32
#define LL 512
#define HH 768
#define NN 64
#define NLAYERS 4

// ---------------------------------------------------------------------------
// Kernel 0: build S4 conv kernels for all layers.
// Kf row per (il,h) has 1024 floats: Kf[512+d]=K0[d] (d in [0,511]),
// Kf[512-m]=K1[m-1] (m in [1,511]); Kf[0] unused.
// y[t] = sum_tau u[tau]*Kf[512+t-tau]  (exactly the reference circular conv)
// ---------------------------------------------------------------------------
__global__ __launch_bounds__(256) void compute_k_kernel(
    const float* __restrict__ log_dt, const float* __restrict__ A_re,
    const float* __restrict__ A_im, const float* __restrict__ C_re,
    const float* __restrict__ C_im, float* __restrict__ Kf) {
  int blk = blockIdx.x;            // il*HH + h
  int tid = threadIdx.x;
  __shared__ float s_er[NN], s_ei[NN], s_c0r[NN], s_c0i[NN], s_c1r[NN], s_c1i[NN];
  if (tid < NN) {
    int n = tid;
    int il = blk / HH, h = blk - il * HH;
    float dt = expf(log_dt[blk]);
    float a_re = -expf(A_re[(size_t)blk * NN + n]);
    float a_im = A_im[(size_t)blk * NN + n];
    float er = dt * a_re, ei = dt * a_im;        // dtA
    float ea = expf(er);
    float sv, cv;
    sincosf(ei, &sv, &cv);
    float e1r = ea * cv - 1.0f, e1i = ea * sv;   // exp(dtA)-1
    float den = a_re * a_re + a_im * a_im;
    float wr = (e1r * a_re + e1i * a_im) / den;  // (exp(dtA)-1)/A
    float wi = (e1i * a_re - e1r * a_im) / den;
    size_t c0 = ((size_t)(il * 2 + 0) * HH + h) * NN + n;
    size_t c1 = ((size_t)(il * 2 + 1) * HH + h) * NN + n;
    float c0r = C_re[c0], c0i = C_im[c0];
    float c1r = C_re[c1], c1i = C_im[c1];
    s_er[n] = er; s_ei[n] = ei;
    s_c0r[n] = c0r * wr - c0i * wi;  s_c0i[n] = c0r * wi + c0i * wr;
    s_c1r[n] = c1r * wr - c1i * wi;  s_c1i[n] = c1r * wi + c1i * wr;
  }
  __syncthreads();
  float* row = Kf + (size_t)blk * 1024;
  for (int l = tid; l < LL; l += 256) {
    float fl = (float)l;
    float k0 = 0.f, k1 = 0.f;
#pragma unroll 4
    for (int n = 0; n < NN; ++n) {
      float amp = expf(s_er[n] * fl);
      float sv, cv;
      sincosf(s_ei[n] * fl, &sv, &cv);
      float vr = amp * cv, vi = amp * sv;
      k0 = fmaf(s_c0r[n], vr, k0); k0 = fmaf(-s_c0i[n], vi, k0);
      k1 = fmaf(s_c1r[n], vr, k1); k1 = fmaf(-s_c1i[n], vi, k1);
    }
    row[512 + l] = 2.f * k0;
    row[511 - l] = 2.f * k1;
  }
}

// ---------------------------------------------------------------------------
// LayerNorm (wave per row of 768) * mask -> Y
// ---------------------------------------------------------------------------
__global__ __launch_bounds__(256) void ln_mask_kernel(
    const float* __restrict__ X, const float* __restrict__ w,
    const float* __restrict__ b, const int* __restrict__ mask,
    float* __restrict__ Y) {
  int wv = threadIdx.x >> 6, lane = threadIdx.x & 63;
  size_t r = (size_t)blockIdx.x * 4 + wv;       // row over B*L
  const float4* xr = (const float4*)(X + r * HH);
  float4 v[3];
  float s = 0.f, s2 = 0.f;
#pragma unroll
  for (int m = 0; m < 3; ++m) {
    v[m] = xr[lane + 64 * m];
    s  += v[m].x + v[m].y + v[m].z + v[m].w;
    s2 += v[m].x * v[m].x + v[m].y * v[m].y + v[m].z * v[m].z + v[m].w * v[m].w;
  }
#pragma unroll
  for (int off = 32; off >= 1; off >>= 1) {
    s  += __shfl_xor(s, off);
    s2 += __shfl_xor(s2, off);
  }
  float mu  = s * (1.f / HH);
  float var = s2 * (1.f / HH) - mu * mu;
  float rs  = rsqrtf(var + 1e-5f);
  float mf  = (float)mask[r];
  const float4* w4 = (const float4*)w;
  const float4* b4 = (const float4*)b;
  float4* yr = (float4*)(Y + r * HH);
#pragma unroll
  for (int m = 0; m < 3; ++m) {
    float4 ww = w4[lane + 64 * m], bb = b4[lane + 64 * m], o;
    o.x = ((v[m].x - mu) * rs * ww.x + bb.x) * mf;
    o.y = ((v[m].y - mu) * rs * ww.y + bb.y) * mf;
    o.z = ((v[m].z - mu) * rs * ww.z + bb.z) * mf;
    o.w = ((v[m].w - mu) * rs * ww.w + bb.w) * mf;
    yr[lane + 64 * m] = o;
  }
}

// ---------------------------------------------------------------------------
// LayerNorm(G) + residual into X (X += LN(G)), wave per row
// ---------------------------------------------------------------------------
__global__ __launch_bounds__(256) void ln_residual_kernel(
    const float* __restrict__ G, const float* __restrict__ w,
    const float* __restrict__ b, float* __restrict__ X) {
  int wv = threadIdx.x >> 6, lane = threadIdx.x & 63;
  size_t r = (size_t)blockIdx.x * 4 + wv;
  const float4* gr = (const float4*)(G + r * HH);
  float4 v[3];
  float s = 0.f, s2 = 0.f;
#pragma unroll
  for (int m = 0; m < 3; ++m) {
    v[m] = gr[lane + 64 * m];
    s  += v[m].x + v[m].y + v[m].z + v[m].w;
    s2 += v[m].x * v[m].x + v[m].y * v[m].y + v[m].z * v[m].z + v[m].w * v[m].w;
  }
#pragma unroll
  for (int off = 32; off >= 1; off >>= 1) {
    s  += __shfl_xor(s, off);
    s2 += __shfl_xor(s2, off);
  }
  float mu  = s * (1.f / HH);
  float var = s2 * (1.f / HH) - mu * mu;
  float rs  = rsqrtf(var + 1e-5f);
  const float4* w4 = (const float4*)w;
  const float4* b4 = (const float4*)b;
  float4* xr = (float4*)(X + r * HH);
#pragma unroll
  for (int m = 0; m < 3; ++m) {
    float4 ww = w4[lane + 64 * m], bb = b4[lane + 64 * m];
    float4 xv = xr[lane + 64 * m];
    xv.x += (v[m].x - mu) * rs * ww.x + bb.x;
    xv.y += (v[m].y - mu) * rs * ww.y + bb.y;
    xv.z += (v[m].z - mu) * rs * ww.z + bb.z;
    xv.w += (v[m].w - mu) * rs * ww.w + bb.w;
    xr[lane + 64 * m] = xv;
  }
}

// ---------------------------------------------------------------------------
// Transpose [B,L,H] -> [B,H,L], 32x32 tiles
// ---------------------------------------------------------------------------
__global__ __launch_bounds__(256) void transpose_kernel(
    const float* __restrict__ X, float* __restrict__ U) {
  __shared__ float tile[32][33];
  int b = blockIdx.z;
  int h0 = blockIdx.x << 5, l0 = blockIdx.y << 5;
  int tx = threadIdx.x, ty = threadIdx.y;   // 32 x 8
#pragma unroll
  for (int k = 0; k < 4; ++k)
    tile[ty + 8 * k][tx] = X[((size_t)b * LL + l0 + ty + 8 * k) * HH + h0 + tx];
  __syncthreads();
#pragma unroll
  for (int k = 0; k < 4; ++k)
    U[((size_t)b * HH + h0 + ty + 8 * k) * LL + l0 + tx] = tile[tx][ty + 8 * k];
}

// ---------------------------------------------------------------------------
// Bidirectional conv + D*u + gelu(tanh), in place on U[B,H,L].
// One wave per (b,h) row. Lane j owns t = 8j..8j+7; sliding K window in
// registers with 8-phase rotation (1 new LDS read per tau).
// LDS K is stored padded at i+(i>>3) so the stride-8 lane access is
// conflict-free (stride 9 mod 32 banks).
// ---------------------------------------------------------------------------
__global__ __launch_bounds__(256) void conv_kernel(
    float* __restrict__ U, const float* __restrict__ Kf,
    const float* __restrict__ Dv) {
  __shared__ float sh[4][512 + 1152];
  int wv = threadIdx.x >> 6, lane = threadIdx.x & 63;
  int p = blockIdx.x * 4 + wv;     // row index over B*H
  int h = p % HH;
  float* su  = sh[wv];
  float* skf = sh[wv] + 512;

  float* urow = U + (size_t)p * LL;
  const float4* ug = (const float4*)urow;
  float4* su4 = (float4*)su;
  for (int i = lane; i < 128; i += 64) su4[i] = ug[i];
  const float* kr = Kf + (size_t)h * 1024;
  for (int i = lane; i < 1024; i += 64) skf[i + (i >> 3)] = kr[i];
  __syncthreads();

  float rg[8], acc[8];
#pragma unroll
  for (int s = 0; s < 8; ++s) {
    int q = 512 + 8 * lane + s;    // K(8j+s) at tau=0
    rg[s] = skf[q + (q >> 3)];
    acc[s] = 0.f;
  }
  int qbase = 511 + 8 * lane;      // logical index for the tau=0 refill
  for (int t8 = 0; t8 < 64; ++t8) {
    float4 uA = su4[t8 * 2], uB = su4[t8 * 2 + 1];
    float uvals[8] = {uA.x, uA.y, uA.z, uA.w, uB.x, uB.y, uB.z, uB.w};
#pragma unroll
    for (int ph = 0; ph < 8; ++ph) {
      float uv = uvals[ph];
#pragma unroll
      for (int s = 0; s < 8; ++s)
        acc[s] = fmaf(uv, rg[(s - ph) & 7], acc[s]);
      int q = qbase - (t8 * 8 + ph);       // K(8j - tau - 1)
      rg[(7 - ph) & 7] = skf[q + (q >> 3)];
    }
  }

  float dv = Dv[h];
  float o8[8];
#pragma unroll
  for (int s = 0; s < 8; ++s) {
    int t = 8 * lane + s;
    float y = acc[s] + dv * su[t];
    float g = 0.5f * y * (1.f + tanhf(0.7978845608028654f * (y + 0.044715f * y * y * y)));
    o8[s] = g;
  }
  float4* og = (float4*)urow;
  og[2 * lane]     = make_float4(o8[0], o8[1], o8[2], o8[3]);
  og[2 * lane + 1] = make_float4(o8[4], o8[5], o8[6], o8[7]);
}

// ---------------------------------------------------------------------------
// GEMM: G[b,l,o] = sum_h Y[b,h,l] * W[o,h] + bias[o]
// Reads A tiles straight from the [B,H,L] layout (no transpose-back).
// 64x64 tile, BK=16, 4x4 per thread, fp32.
// ---------------------------------------------------------------------------
__global__ __launch_bounds__(256) void gemm_kernel(
    const float* __restrict__ Y, const float* __restrict__ W,
    const float* __restrict__ bias, float* __restrict__ G) {
  __shared__ float As[16][68];   // As[k][m] = Y[b, h0+k, l0+m]
  __shared__ float Bs[16][68];   // Bs[k][n] = W[o0+n, h0+k]
  int ob = blockIdx.x, mb = blockIdx.y;
  int b  = mb >> 3;
  int l0 = (mb & 7) << 6;
  int o0 = ob << 6;
  int tid = threadIdx.x;
  int tm = tid & 15, tn = tid >> 4;

  float acc[4][4];
#pragma unroll
  for (int i = 0; i < 4; ++i)
#pragma unroll
    for (int j = 0; j < 4; ++j) acc[i][j] = 0.f;

  int am = tid & 63, ak = tid >> 6;       // A loader
  int bn = tid >> 2, bk = (tid & 3) << 2; // B loader

  for (int h0 = 0; h0 < HH; h0 += 16) {
#pragma unroll
    for (int kk = ak; kk < 16; kk += 4)
      As[kk][am] = Y[((size_t)b * HH + h0 + kk) * LL + l0 + am];
    float4 wvq = *(const float4*)&W[(size_t)(o0 + bn) * HH + h0 + bk];
    Bs[bk + 0][bn] = wvq.x;
    Bs[bk + 1][bn] = wvq.y;
    Bs[bk + 2][bn] = wvq.z;
    Bs[bk + 3][bn] = wvq.w;
    __syncthreads();
#pragma unroll
    for (int kk = 0; kk < 16; ++kk) {
      float4 a  = *(const float4*)&As[kk][tm << 2];
      float4 bq = *(const float4*)&Bs[kk][tn << 2];
      acc[0][0] = fmaf(a.x, bq.x, acc[0][0]);
      acc[0][1] = fmaf(a.x, bq.y, acc[0][1]);
      acc[0][2] = fmaf(a.x, bq.z, acc[0][2]);
      acc[0][3] = fmaf(a.x, bq.w, acc[0][3]);
      acc[1][0] = fmaf(a.y, bq.x, acc[1][0]);
      acc[1][1] = fmaf(a.y, bq.y, acc[1][1]);
      acc[1][2] = fmaf(a.y, bq.z, acc[1][2]);
      acc[1][3] = fmaf(a.y, bq.w, acc[1][3]);
      acc[2][0] = fmaf(a.z, bq.x, acc[2][0]);
      acc[2][1] = fmaf(a.z, bq.y, acc[2][1]);
      acc[2][2] = fmaf(a.z, bq.z, acc[2][2]);
      acc[2][3] = fmaf(a.z, bq.w, acc[2][3]);
      acc[3][0] = fmaf(a.w, bq.x, acc[3][0]);
      acc[3][1] = fmaf(a.w, bq.y, acc[3][1]);
      acc[3][2] = fmaf(a.w, bq.z, acc[3][2]);
      acc[3][3] = fmaf(a.w, bq.w, acc[3][3]);
    }
    __syncthreads();
  }

  float4 bb = *(const float4*)&bias[o0 + (tn << 2)];
#pragma unroll
  for (int im = 0; im < 4; ++im) {
    float4 res;
    res.x = acc[im][0] + bb.x;
    res.y = acc[im][1] + bb.y;
    res.z = acc[im][2] + bb.z;
    res.w = acc[im][3] + bb.w;
    *(float4*)&G[((size_t)b * LL + l0 + (tm << 2) + im) * HH + o0 + (tn << 2)] = res;
  }
}

// ---------------------------------------------------------------------------
extern "C" void kernel_launch(void* const* d_in, const int* in_sizes, int n_in,
                              void* d_out, int out_size, void* d_ws, size_t ws_size,
                              hipStream_t stream) {
  const float* x      = (const float*)d_in[0];
  const int*   mask   = (const int*)d_in[1];
  const float* ln1_w  = (const float*)d_in[2];
  const float* ln1_b  = (const float*)d_in[3];
  const float* log_dt = (const float*)d_in[4];
  const float* A_re   = (const float*)d_in[5];
  const float* A_im   = (const float*)d_in[6];
  const float* C_re   = (const float*)d_in[7];
  const float* C_im   = (const float*)d_in[8];
  const float* Dv     = (const float*)d_in[9];
  const float* Wout   = (const float*)d_in[10];
  const float* bout   = (const float*)d_in[11];
  const float* ln2_w  = (const float*)d_in[12];
  const float* ln2_b  = (const float*)d_in[13];
  float* out = (float*)d_out;

  float* ws   = (float*)d_ws;
  float* Kf   = ws;                                   // NL*H*1024 floats
  float* buf0 = Kf + (size_t)NLAYERS * HH * 1024;     // B*L*H
  float* buf1 = buf0 + (size_t)BB * LL * HH;          // B*H*L

  size_t xbytes = (size_t)BB * LL * HH * sizeof(float);
  hipMemcpyAsync(out, x, xbytes, hipMemcpyDeviceToDevice, stream);

  compute_k_kernel<<<NLAYERS * HH, 256, 0, stream>>>(log_dt, A_re, A_im, C_re, C_im, Kf);

  for (int il = 0; il < NLAYERS; ++il) {
    ln_mask_kernel<<<BB * LL / 4, 256, 0, stream>>>(
        out, ln1_w + il * HH, ln1_b + il * HH, mask, buf0);
    transpose_kernel<<<dim3(HH / 32, LL / 32, BB), dim3(32, 8), 0, stream>>>(buf0, buf1);
    conv_kernel<<<BB * HH / 4, 256, 0, stream>>>(
        buf1, Kf + (size_t)il * HH * 1024, Dv + il * HH);
    gemm_kernel<<<dim3(HH / 64, BB * LL / 64), 256, 0, stream>>>(
        buf1, Wout + (size_t)il * HH * HH, bout + il * HH, buf0);
    ln_residual_kernel<<<BB * LL / 4, 256, 0, stream>>>(
        buf0, ln2_w + il * HH, ln2_b + il * HH, out);
  }
}

// Round 3
// 1560.292 us; speedup vs baseline: 1.6075x; 1.6075x over previous
//
#include <hip/hip_runtime.h>
#include <math.h>

#define BB 32
#define LL 512
#define HH 768
#define NN 64
#define NLAYERS 4

typedef unsigned short ushort;
typedef __attribute__((ext_vector_type(8))) short bf16x8;
typedef __attribute__((ext_vector_type(4))) float f32x4;

static __device__ __forceinline__ ushort f2bf(float f) {
  union { float f; unsigned u; } v; v.f = f;
  unsigned r = (v.u + 0x7FFF + ((v.u >> 16) & 1)) >> 16;   // RNE
  return (ushort)r;
}

static __device__ __forceinline__ void gload16(const void* g, void* l) {
  __builtin_amdgcn_global_load_lds(
      (const __attribute__((address_space(1))) unsigned int*)g,
      (__attribute__((address_space(3))) unsigned int*)l, 16, 0, 0);
}

// ---------------------------------------------------------------------------
// Kernel 0: build S4 conv kernels for all layers (unchanged).
// Kf[512+d]=K0[d], Kf[512-m]=K1[m-1];  y[t] = sum_tau u[tau]*Kf[512+t-tau]
// ---------------------------------------------------------------------------
__global__ __launch_bounds__(256) void compute_k_kernel(
    const float* __restrict__ log_dt, const float* __restrict__ A_re,
    const float* __restrict__ A_im, const float* __restrict__ C_re,
    const float* __restrict__ C_im, float* __restrict__ Kf) {
  int blk = blockIdx.x;            // il*HH + h
  int tid = threadIdx.x;
  __shared__ float s_er[NN], s_ei[NN], s_c0r[NN], s_c0i[NN], s_c1r[NN], s_c1i[NN];
  if (tid < NN) {
    int n = tid;
    int il = blk / HH, h = blk - il * HH;
    float dt = expf(log_dt[blk]);
    float a_re = -expf(A_re[(size_t)blk * NN + n]);
    float a_im = A_im[(size_t)blk * NN + n];
    float er = dt * a_re, ei = dt * a_im;
    float ea = expf(er);
    float sv, cv;
    sincosf(ei, &sv, &cv);
    float e1r = ea * cv - 1.0f, e1i = ea * sv;
    float den = a_re * a_re + a_im * a_im;
    float wr = (e1r * a_re + e1i * a_im) / den;
    float wi = (e1i * a_re - e1r * a_im) / den;
    size_t c0 = ((size_t)(il * 2 + 0) * HH + h) * NN + n;
    size_t c1 = ((size_t)(il * 2 + 1) * HH + h) * NN + n;
    float c0r = C_re[c0], c0i = C_im[c0];
    float c1r = C_re[c1], c1i = C_im[c1];
    s_er[n] = er; s_ei[n] = ei;
    s_c0r[n] = c0r * wr - c0i * wi;  s_c0i[n] = c0r * wi + c0i * wr;
    s_c1r[n] = c1r * wr - c1i * wi;  s_c1i[n] = c1r * wi + c1i * wr;
  }
  __syncthreads();
  float* row = Kf + (size_t)blk * 1024;
  for (int l = tid; l < LL; l += 256) {
    float fl = (float)l;
    float k0 = 0.f, k1 = 0.f;
#pragma unroll 4
    for (int n = 0; n < NN; ++n) {
      float amp = expf(s_er[n] * fl);
      float sv, cv;
      sincosf(s_ei[n] * fl, &sv, &cv);
      float vr = amp * cv, vi = amp * sv;
      k0 = fmaf(s_c0r[n], vr, k0); k0 = fmaf(-s_c0i[n], vi, k0);
      k1 = fmaf(s_c1r[n], vr, k1); k1 = fmaf(-s_c1i[n], vi, k1);
    }
    row[512 + l] = 2.f * k0;
    row[511 - l] = 2.f * k1;
  }
}

// ---------------------------------------------------------------------------
// Wout fp32 -> bf16 (once, all layers)
// ---------------------------------------------------------------------------
__global__ __launch_bounds__(256) void wcast_kernel(
    const float* __restrict__ W, ushort* __restrict__ Wbf) {
  size_t i = ((size_t)blockIdx.x * 256 + threadIdx.x) * 8;
  float4 a = *(const float4*)&W[i];
  float4 c = *(const float4*)&W[i + 4];
  ushort o[8] = {f2bf(a.x), f2bf(a.y), f2bf(a.z), f2bf(a.w),
                 f2bf(c.x), f2bf(c.y), f2bf(c.z), f2bf(c.w)};
  *(bf16x8*)&Wbf[i] = *(bf16x8*)o;
}

// ---------------------------------------------------------------------------
// LayerNorm * mask -> Y (unchanged)
// ---------------------------------------------------------------------------
__global__ __launch_bounds__(256) void ln_mask_kernel(
    const float* __restrict__ X, const float* __restrict__ w,
    const float* __restrict__ b, const int* __restrict__ mask,
    float* __restrict__ Y) {
  int wv = threadIdx.x >> 6, lane = threadIdx.x & 63;
  size_t r = (size_t)blockIdx.x * 4 + wv;
  const float4* xr = (const float4*)(X + r * HH);
  float4 v[3];
  float s = 0.f, s2 = 0.f;
#pragma unroll
  for (int m = 0; m < 3; ++m) {
    v[m] = xr[lane + 64 * m];
    s  += v[m].x + v[m].y + v[m].z + v[m].w;
    s2 += v[m].x * v[m].x + v[m].y * v[m].y + v[m].z * v[m].z + v[m].w * v[m].w;
  }
#pragma unroll
  for (int off = 32; off >= 1; off >>= 1) {
    s  += __shfl_xor(s, off);
    s2 += __shfl_xor(s2, off);
  }
  float mu  = s * (1.f / HH);
  float var = s2 * (1.f / HH) - mu * mu;
  float rs  = rsqrtf(var + 1e-5f);
  float mf  = (float)mask[r];
  const float4* w4 = (const float4*)w;
  const float4* b4 = (const float4*)b;
  float4* yr = (float4*)(Y + r * HH);
#pragma unroll
  for (int m = 0; m < 3; ++m) {
    float4 ww = w4[lane + 64 * m], bb = b4[lane + 64 * m], o;
    o.x = ((v[m].x - mu) * rs * ww.x + bb.x) * mf;
    o.y = ((v[m].y - mu) * rs * ww.y + bb.y) * mf;
    o.z = ((v[m].z - mu) * rs * ww.z + bb.z) * mf;
    o.w = ((v[m].w - mu) * rs * ww.w + bb.w) * mf;
    yr[lane + 64 * m] = o;
  }
}

// ---------------------------------------------------------------------------
// LayerNorm(G) + residual into X (unchanged)
// ---------------------------------------------------------------------------
__global__ __launch_bounds__(256) void ln_residual_kernel(
    const float* __restrict__ G, const float* __restrict__ w,
    const float* __restrict__ b, float* __restrict__ X) {
  int wv = threadIdx.x >> 6, lane = threadIdx.x & 63;
  size_t r = (size_t)blockIdx.x * 4 + wv;
  const float4* gr = (const float4*)(G + r * HH);
  float4 v[3];
  float s = 0.f, s2 = 0.f;
#pragma unroll
  for (int m = 0; m < 3; ++m) {
    v[m] = gr[lane + 64 * m];
    s  += v[m].x + v[m].y + v[m].z + v[m].w;
    s2 += v[m].x * v[m].x + v[m].y * v[m].y + v[m].z * v[m].z + v[m].w * v[m].w;
  }
#pragma unroll
  for (int off = 32; off >= 1; off >>= 1) {
    s  += __shfl_xor(s, off);
    s2 += __shfl_xor(s2, off);
  }
  float mu  = s * (1.f / HH);
  float var = s2 * (1.f / HH) - mu * mu;
  float rs  = rsqrtf(var + 1e-5f);
  const float4* w4 = (const float4*)w;
  const float4* b4 = (const float4*)b;
  float4* xr = (float4*)(X + r * HH);
#pragma unroll
  for (int m = 0; m < 3; ++m) {
    float4 ww = w4[lane + 64 * m], bb = b4[lane + 64 * m];
    float4 xv = xr[lane + 64 * m];
    xv.x += (v[m].x - mu) * rs * ww.x + bb.x;
    xv.y += (v[m].y - mu) * rs * ww.y + bb.y;
    xv.z += (v[m].z - mu) * rs * ww.z + bb.z;
    xv.w += (v[m].w - mu) * rs * ww.w + bb.w;
    xr[lane + 64 * m] = xv;
  }
}

// ---------------------------------------------------------------------------
// Transpose [B,L,H] -> [B,H,L] fp32 (unchanged)
// ---------------------------------------------------------------------------
__global__ __launch_bounds__(256) void transpose_kernel(
    const float* __restrict__ X, float* __restrict__ U) {
  __shared__ float tile[32][33];
  int b = blockIdx.z;
  int h0 = blockIdx.x << 5, l0 = blockIdx.y << 5;
  int tx = threadIdx.x, ty = threadIdx.y;
#pragma unroll
  for (int k = 0; k < 4; ++k)
    tile[ty + 8 * k][tx] = X[((size_t)b * LL + l0 + ty + 8 * k) * HH + h0 + tx];
  __syncthreads();
#pragma unroll
  for (int k = 0; k < 4; ++k)
    U[((size_t)b * HH + h0 + ty + 8 * k) * LL + l0 + tx] = tile[tx][ty + 8 * k];
}

// ---------------------------------------------------------------------------
// [B,H,L] fp32 -> [B,L,H] bf16  (transpose + cast; feeds the MFMA GEMM)
// ---------------------------------------------------------------------------
__global__ __launch_bounds__(256) void t2bf_kernel(
    const float* __restrict__ U, ushort* __restrict__ Ybf) {
  __shared__ float tile[32][33];
  int b = blockIdx.z;
  int l0 = blockIdx.x << 5, h0 = blockIdx.y << 5;
  int tx = threadIdx.x, ty = threadIdx.y;
#pragma unroll
  for (int k = 0; k < 4; ++k)
    tile[ty + 8 * k][tx] = U[((size_t)b * HH + h0 + ty + 8 * k) * LL + l0 + tx];
  __syncthreads();
#pragma unroll
  for (int k = 0; k < 4; ++k)
    Ybf[((size_t)b * LL + l0 + ty + 8 * k) * HH + h0 + tx] = f2bf(tile[tx][ty + 8 * k]);
}

// ---------------------------------------------------------------------------
// Bidirectional conv + D*u + gelu, in place on U[B,H,L] (unchanged)
// ---------------------------------------------------------------------------
__global__ __launch_bounds__(256) void conv_kernel(
    float* __restrict__ U, const float* __restrict__ Kf,
    const float* __restrict__ Dv) {
  __shared__ float sh[4][512 + 1152];
  int wv = threadIdx.x >> 6, lane = threadIdx.x & 63;
  int p = blockIdx.x * 4 + wv;
  int h = p % HH;
  float* su  = sh[wv];
  float* skf = sh[wv] + 512;

  float* urow = U + (size_t)p * LL;
  const float4* ug = (const float4*)urow;
  float4* su4 = (float4*)su;
  for (int i = lane; i < 128; i += 64) su4[i] = ug[i];
  const float* kr = Kf + (size_t)h * 1024;
  for (int i = lane; i < 1024; i += 64) skf[i + (i >> 3)] = kr[i];
  __syncthreads();

  float rg[8], acc[8];
#pragma unroll
  for (int s = 0; s < 8; ++s) {
    int q = 512 + 8 * lane + s;
    rg[s] = skf[q + (q >> 3)];
    acc[s] = 0.f;
  }
  int qbase = 511 + 8 * lane;
  for (int t8 = 0; t8 < 64; ++t8) {
    float4 uA = su4[t8 * 2], uB = su4[t8 * 2 + 1];
    float uvals[8] = {uA.x, uA.y, uA.z, uA.w, uB.x, uB.y, uB.z, uB.w};
#pragma unroll
    for (int ph = 0; ph < 8; ++ph) {
      float uv = uvals[ph];
#pragma unroll
      for (int s = 0; s < 8; ++s)
        acc[s] = fmaf(uv, rg[(s - ph) & 7], acc[s]);
      int q = qbase - (t8 * 8 + ph);
      rg[(7 - ph) & 7] = skf[q + (q >> 3)];
    }
  }

  float dv = Dv[h];
  float o8[8];
#pragma unroll
  for (int s = 0; s < 8; ++s) {
    int t = 8 * lane + s;
    float y = acc[s] + dv * su[t];
    float g = 0.5f * y * (1.f + tanhf(0.7978845608028654f * (y + 0.044715f * y * y * y)));
    o8[s] = g;
  }
  float4* og = (float4*)urow;
  og[2 * lane]     = make_float4(o8[0], o8[1], o8[2], o8[3]);
  og[2 * lane + 1] = make_float4(o8[4], o8[5], o8[6], o8[7]);
}

// ---------------------------------------------------------------------------
// bf16 MFMA GEMM: G[b,l,o] = sum_h Ybf[b,l,h]*Wbf[o,h] + bias[o]   (fp32 out)
// 128x128 tile, BK=64, 4 waves (2x2), 16x16x32 MFMA.
// global_load_lds(16B) staging, pre-swizzled source + swizzled ds_read (T2).
// ---------------------------------------------------------------------------
__global__ __launch_bounds__(256) void gemm_kernel(
    const ushort* __restrict__ Ybf, const ushort* __restrict__ Wbf,
    const float* __restrict__ bias, float* __restrict__ G) {
  __shared__ ushort As[128 * 64];   // [m][k], 16KB, rows 128B, XOR-swizzled
  __shared__ ushort Bs[128 * 64];   // [n][k]
  int tid = threadIdx.x;
  int wv = tid >> 6, lane = tid & 63;
  int wm = wv >> 1, wn = wv & 1;          // wave -> 64x64 quadrant
  int b  = blockIdx.y >> 2;
  int l0 = (blockIdx.y & 3) << 7;
  int o0 = blockIdx.x << 7;

  // staging addresses (per wave: 4 A-loads + 4 B-loads of 1KB each)
  int swz8 = (((lane & 7) ^ (lane >> 3)) << 3);   // element offset in 64-elem row
  int rsub = (lane >> 3);                          // row within 8-row group
  size_t arow0 = (size_t)(b * LL + l0 + wv * 32 + rsub) * HH;
  size_t brow0 = (size_t)(o0 + wv * 32 + rsub) * HH;
  char* Adst = (char*)As + wv * 4096;
  char* Bdst = (char*)Bs + wv * 4096;

  f32x4 acc[4][4];
#pragma unroll
  for (int i = 0; i < 4; ++i)
#pragma unroll
    for (int j = 0; j < 4; ++j) acc[i][j] = (f32x4){0.f, 0.f, 0.f, 0.f};

  for (int kt = 0; kt < HH / 64; ++kt) {
    int h0 = kt * 64;
#pragma unroll
    for (int i = 0; i < 4; ++i) {
      gload16(Ybf + arow0 + (size_t)i * 8 * HH + h0 + swz8, Adst + i * 1024);
      gload16(Wbf + brow0 + (size_t)i * 8 * HH + h0 + swz8, Bdst + i * 1024);
    }
    __syncthreads();

    bf16x8 af[4][2], bfr[4][2];
#pragma unroll
    for (int mi = 0; mi < 4; ++mi) {
      int m = wm * 64 + mi * 16 + (lane & 15);
#pragma unroll
      for (int kk = 0; kk < 2; ++kk) {
        int off = m * 128 + ((((lane >> 4) << 4) + (kk << 6)) ^ ((lane & 7) << 4));
        af[mi][kk] = *(const bf16x8*)((const char*)As + off);
      }
    }
#pragma unroll
    for (int ni = 0; ni < 4; ++ni) {
      int n = wn * 64 + ni * 16 + (lane & 15);
#pragma unroll
      for (int kk = 0; kk < 2; ++kk) {
        int off = n * 128 + ((((lane >> 4) << 4) + (kk << 6)) ^ ((lane & 7) << 4));
        bfr[ni][kk] = *(const bf16x8*)((const char*)Bs + off);
      }
    }
#pragma unroll
    for (int kk = 0; kk < 2; ++kk)
#pragma unroll
      for (int mi = 0; mi < 4; ++mi)
#pragma unroll
        for (int ni = 0; ni < 4; ++ni)
          acc[mi][ni] = __builtin_amdgcn_mfma_f32_16x16x32_bf16(
              af[mi][kk], bfr[ni][kk], acc[mi][ni], 0, 0, 0);
    __syncthreads();
  }

  // epilogue: C/D layout col=lane&15 (n), row=(lane>>4)*4+j (m)
#pragma unroll
  for (int ni = 0; ni < 4; ++ni) {
    int n_g = o0 + wn * 64 + ni * 16 + (lane & 15);
    float bv = bias[n_g];
#pragma unroll
    for (int mi = 0; mi < 4; ++mi) {
      int m_g = l0 + wm * 64 + mi * 16 + ((lane >> 4) << 2);
      float* gp = G + ((size_t)b * LL + m_g) * HH + n_g;
#pragma unroll
      for (int j = 0; j < 4; ++j)
        gp[(size_t)j * HH] = acc[mi][ni][j] + bv;
    }
  }
}

// ---------------------------------------------------------------------------
extern "C" void kernel_launch(void* const* d_in, const int* in_sizes, int n_in,
                              void* d_out, int out_size, void* d_ws, size_t ws_size,
                              hipStream_t stream) {
  const float* x      = (const float*)d_in[0];
  const int*   mask   = (const int*)d_in[1];
  const float* ln1_w  = (const float*)d_in[2];
  const float* ln1_b  = (const float*)d_in[3];
  const float* log_dt = (const float*)d_in[4];
  const float* A_re   = (const float*)d_in[5];
  const float* A_im   = (const float*)d_in[6];
  const float* C_re   = (const float*)d_in[7];
  const float* C_im   = (const float*)d_in[8];
  const float* Dv     = (const float*)d_in[9];
  const float* Wout   = (const float*)d_in[10];
  const float* bout   = (const float*)d_in[11];
  const float* ln2_w  = (const float*)d_in[12];
  const float* ln2_b  = (const float*)d_in[13];
  float* out = (float*)d_out;

  float*  ws   = (float*)d_ws;
  float*  Kf   = ws;                                   // NL*H*1024 f32
  float*  buf0 = Kf + (size_t)NLAYERS * HH * 1024;     // B*L*H f32 (also Ybf bf16)
  float*  buf1 = buf0 + (size_t)BB * LL * HH;          // B*H*L f32 (also G f32)
  ushort* Wbf  = (ushort*)(buf1 + (size_t)BB * LL * HH); // NL*H*H bf16

  size_t xbytes = (size_t)BB * LL * HH * sizeof(float);
  hipMemcpyAsync(out, x, xbytes, hipMemcpyDeviceToDevice, stream);

  compute_k_kernel<<<NLAYERS * HH, 256, 0, stream>>>(log_dt, A_re, A_im, C_re, C_im, Kf);
  wcast_kernel<<<(NLAYERS * HH * HH) / (256 * 8), 256, 0, stream>>>(Wout, Wbf);

  for (int il = 0; il < NLAYERS; ++il) {
    ln_mask_kernel<<<BB * LL / 4, 256, 0, stream>>>(
        out, ln1_w + il * HH, ln1_b + il * HH, mask, buf0);
    transpose_kernel<<<dim3(HH / 32, LL / 32, BB), dim3(32, 8), 0, stream>>>(buf0, buf1);
    conv_kernel<<<BB * HH / 4, 256, 0, stream>>>(
        buf1, Kf + (size_t)il * HH * 1024, Dv + il * HH);
    t2bf_kernel<<<dim3(LL / 32, HH / 32, BB), dim3(32, 8), 0, stream>>>(
        buf1, (ushort*)buf0);
    gemm_kernel<<<dim3(HH / 128, BB * LL / 128), 256, 0, stream>>>(
        (const ushort*)buf0, Wbf + (size_t)il * HH * HH, bout + il * HH, buf1);
    ln_residual_kernel<<<BB * LL / 4, 256, 0, stream>>>(
        buf1, ln2_w + il * HH, ln2_b + il * HH, out);
  }
}

// Round 4
// 711.840 us; speedup vs baseline: 3.5236x; 2.1919x over previous
//
#include <hip/hip_runtime.h>
#include <math.h>

#define BB 32
#define LL 512
#define HH 768
#define NN 64
#define NLAYERS 4

typedef unsigned short ushort;
typedef __attribute__((ext_vector_type(8))) short bf16x8;
typedef __attribute__((ext_vector_type(4))) float f32x4;
typedef __attribute__((ext_vector_type(4))) ushort u16x4;

static __device__ __forceinline__ ushort f2bf(float f) {
  union { float f; unsigned u; } v; v.f = f;
  unsigned r = (v.u + 0x7FFF + ((v.u >> 16) & 1)) >> 16;   // RNE
  return (ushort)r;
}
static __device__ __forceinline__ float bf2f(ushort u) {
  union { unsigned u; float f; } v; v.u = ((unsigned)u) << 16; return v.f;
}
static __device__ __forceinline__ void gload16(const void* g, void* l) {
  __builtin_amdgcn_global_load_lds(
      (const __attribute__((address_space(1))) unsigned int*)g,
      (__attribute__((address_space(3))) unsigned int*)l, 16, 0, 0);
}

// ---------------------------------------------------------------------------
// Kernel 0: build REVERSED bf16 conv kernels: rev[i] = bf16(Kb[1023-i]) where
// Kb[512+d]=K0[d], Kb[511-m]=K1[m]. Conv: y[t] = sum_tau u[tau]*Kb[512+t-tau].
// ---------------------------------------------------------------------------
__global__ __launch_bounds__(256) void compute_k_kernel(
    const float* __restrict__ log_dt, const float* __restrict__ A_re,
    const float* __restrict__ A_im, const float* __restrict__ C_re,
    const float* __restrict__ C_im, ushort* __restrict__ rev) {
  int blk = blockIdx.x;            // il*HH + h
  int tid = threadIdx.x;
  __shared__ float s_er[NN], s_ei[NN], s_c0r[NN], s_c0i[NN], s_c1r[NN], s_c1i[NN];
  if (tid < NN) {
    int n = tid;
    int il = blk / HH, h = blk - il * HH;
    float dt = expf(log_dt[blk]);
    float a_re = -expf(A_re[(size_t)blk * NN + n]);
    float a_im = A_im[(size_t)blk * NN + n];
    float er = dt * a_re, ei = dt * a_im;
    float ea = expf(er);
    float sv, cv;
    sincosf(ei, &sv, &cv);
    float e1r = ea * cv - 1.0f, e1i = ea * sv;
    float den = a_re * a_re + a_im * a_im;
    float wr = (e1r * a_re + e1i * a_im) / den;
    float wi = (e1i * a_re - e1r * a_im) / den;
    size_t c0 = ((size_t)(il * 2 + 0) * HH + h) * NN + n;
    size_t c1 = ((size_t)(il * 2 + 1) * HH + h) * NN + n;
    float c0r = C_re[c0], c0i = C_im[c0];
    float c1r = C_re[c1], c1i = C_im[c1];
    s_er[n] = er; s_ei[n] = ei;
    s_c0r[n] = c0r * wr - c0i * wi;  s_c0i[n] = c0r * wi + c0i * wr;
    s_c1r[n] = c1r * wr - c1i * wi;  s_c1i[n] = c1r * wi + c1i * wr;
  }
  __syncthreads();
  ushort* row = rev + ((size_t)blk << 10);
  for (int l = tid; l < LL; l += 256) {
    float fl = (float)l;
    float k0 = 0.f, k1 = 0.f;
#pragma unroll 4
    for (int n = 0; n < NN; ++n) {
      float amp = expf(s_er[n] * fl);
      float sv, cv;
      sincosf(s_ei[n] * fl, &sv, &cv);
      float vr = amp * cv, vi = amp * sv;
      k0 = fmaf(s_c0r[n], vr, k0); k0 = fmaf(-s_c0i[n], vi, k0);
      k1 = fmaf(s_c1r[n], vr, k1); k1 = fmaf(-s_c1i[n], vi, k1);
    }
    // Kb[512+l] = 2k0 -> rev[511-l]; Kb[511-l] = 2k1 -> rev[512+l]
    row[511 - l] = f2bf(2.f * k0);
    row[512 + l] = f2bf(2.f * k1);
  }
}

// ---------------------------------------------------------------------------
// Wout fp32 -> bf16 (once)
// ---------------------------------------------------------------------------
__global__ __launch_bounds__(256) void wcast_kernel(
    const float* __restrict__ W, ushort* __restrict__ Wbf) {
  size_t i = ((size_t)blockIdx.x * 256 + threadIdx.x) * 8;
  float4 a = *(const float4*)&W[i];
  float4 c = *(const float4*)&W[i + 4];
  ushort o[8] = {f2bf(a.x), f2bf(a.y), f2bf(a.z), f2bf(a.w),
                 f2bf(c.x), f2bf(c.y), f2bf(c.z), f2bf(c.w)};
  *(bf16x8*)&Wbf[i] = *(bf16x8*)o;
}

// ---------------------------------------------------------------------------
// LayerNorm * mask -> bf16 [B,L,H]
// ---------------------------------------------------------------------------
__global__ __launch_bounds__(256) void ln_mask_kernel(
    const float* __restrict__ X, const float* __restrict__ w,
    const float* __restrict__ b, const int* __restrict__ mask,
    ushort* __restrict__ Y) {
  int wv = threadIdx.x >> 6, lane = threadIdx.x & 63;
  size_t r = (size_t)blockIdx.x * 4 + wv;
  const float4* xr = (const float4*)(X + r * HH);
  float4 v[3];
  float s = 0.f, s2 = 0.f;
#pragma unroll
  for (int m = 0; m < 3; ++m) {
    v[m] = xr[lane + 64 * m];
    s  += v[m].x + v[m].y + v[m].z + v[m].w;
    s2 += v[m].x * v[m].x + v[m].y * v[m].y + v[m].z * v[m].z + v[m].w * v[m].w;
  }
#pragma unroll
  for (int off = 32; off >= 1; off >>= 1) {
    s  += __shfl_xor(s, off);
    s2 += __shfl_xor(s2, off);
  }
  float mu  = s * (1.f / HH);
  float var = s2 * (1.f / HH) - mu * mu;
  float rs  = rsqrtf(var + 1e-5f);
  float mf  = (float)mask[r];
  const float4* w4 = (const float4*)w;
  const float4* b4 = (const float4*)b;
  u16x4* yr = (u16x4*)(Y + r * HH);
#pragma unroll
  for (int m = 0; m < 3; ++m) {
    float4 ww = w4[lane + 64 * m], bb = b4[lane + 64 * m];
    u16x4 o;
    o.x = f2bf(((v[m].x - mu) * rs * ww.x + bb.x) * mf);
    o.y = f2bf(((v[m].y - mu) * rs * ww.y + bb.y) * mf);
    o.z = f2bf(((v[m].z - mu) * rs * ww.z + bb.z) * mf);
    o.w = f2bf(((v[m].w - mu) * rs * ww.w + bb.w) * mf);
    yr[lane + 64 * m] = o;
  }
}

// ---------------------------------------------------------------------------
// LayerNorm(G) + residual into X (unchanged, f32)
// ---------------------------------------------------------------------------
__global__ __launch_bounds__(256) void ln_residual_kernel(
    const float* __restrict__ G, const float* __restrict__ w,
    const float* __restrict__ b, float* __restrict__ X) {
  int wv = threadIdx.x >> 6, lane = threadIdx.x & 63;
  size_t r = (size_t)blockIdx.x * 4 + wv;
  const float4* gr = (const float4*)(G + r * HH);
  float4 v[3];
  float s = 0.f, s2 = 0.f;
#pragma unroll
  for (int m = 0; m < 3; ++m) {
    v[m] = gr[lane + 64 * m];
    s  += v[m].x + v[m].y + v[m].z + v[m].w;
    s2 += v[m].x * v[m].x + v[m].y * v[m].y + v[m].z * v[m].z + v[m].w * v[m].w;
  }
#pragma unroll
  for (int off = 32; off >= 1; off >>= 1) {
    s  += __shfl_xor(s, off);
    s2 += __shfl_xor(s2, off);
  }
  float mu  = s * (1.f / HH);
  float var = s2 * (1.f / HH) - mu * mu;
  float rs  = rsqrtf(var + 1e-5f);
  const float4* w4 = (const float4*)w;
  const float4* b4 = (const float4*)b;
  float4* xr = (float4*)(X + r * HH);
#pragma unroll
  for (int m = 0; m < 3; ++m) {
    float4 ww = w4[lane + 64 * m], bb = b4[lane + 64 * m];
    float4 xv = xr[lane + 64 * m];
    xv.x += (v[m].x - mu) * rs * ww.x + bb.x;
    xv.y += (v[m].y - mu) * rs * ww.y + bb.y;
    xv.z += (v[m].z - mu) * rs * ww.z + bb.z;
    xv.w += (v[m].w - mu) * rs * ww.w + bb.w;
    xr[lane + 64 * m] = xv;
  }
}

// ---------------------------------------------------------------------------
// Transpose bf16 [B,L,H] -> [B,H,L]
// ---------------------------------------------------------------------------
__global__ __launch_bounds__(256) void transpose_bf_kernel(
    const ushort* __restrict__ X, ushort* __restrict__ U) {
  __shared__ ushort tile[32][34];
  int b = blockIdx.z;
  int h0 = blockIdx.x << 5, l0 = blockIdx.y << 5;
  int tx = threadIdx.x, ty = threadIdx.y;
#pragma unroll
  for (int k = 0; k < 4; ++k)
    tile[ty + 8 * k][tx] = X[((size_t)b * LL + l0 + ty + 8 * k) * HH + h0 + tx];
  __syncthreads();
#pragma unroll
  for (int k = 0; k < 4; ++k)
    U[((size_t)b * HH + h0 + ty + 8 * k) * LL + l0 + tx] = tile[tx][ty + 8 * k];
}

// ---------------------------------------------------------------------------
// MFMA Toeplitz conv + D*u + gelu.  One wg per h.
// Y[t,b] = sum_tau Kb[512+t-tau] * U[b,tau]   (A = Toeplitz, B = U)
// Ulds[b][tau] bf16, XOR-swizzled ((b&7)<<4), staged via pre-swizzled gload.
// Ktab: 8 rows x 1048, row r = Arev shifted by 17+r (Arev[i]=Kb[1023-i]),
// so lane cc reads its A-frag as one aligned ds_read_b128.
// Diagonal reuse: frag(m,ks) = frag(m+2,ks+1) -> 2 new A-frags per k-step.
// ---------------------------------------------------------------------------
__global__ __launch_bounds__(256) void conv_mfma_kernel(
    const ushort* __restrict__ Ubf, const ushort* __restrict__ rev,
    const float* __restrict__ Dv, float* __restrict__ Yc) {
  __shared__ ushort Ulds[32 * 512];    // 32 KB
  __shared__ ushort Ktab[8 * 1048];    // 16.4 KB
  int tid = threadIdx.x;
  int w = tid >> 6, lane = tid & 63;
  int h = blockIdx.x;

  // stage U rows (pre-swizzled source, linear LDS dest)
#pragma unroll
  for (int it = 0; it < 8; ++it) {
    int G = it * 256 + tid;
    int b = G >> 6, cg = G & 63;
    gload16(Ubf + (((size_t)b * HH + h) << 9) + ((cg ^ (b & 7)) << 3),
            (char*)Ulds + (size_t)(it * 256 + (tid & 0xFFC0)) * 16);
  }
  // stage Ktab: 8 rows x 131 granules; row r slot p holds Arev[p-17-r]
  const ushort* revh = rev + ((size_t)h << 10);
#pragma unroll
  for (int it = 0; it < 5; ++it) {
    int G = it * 256 + tid;
    if (G < 1048) {
      int r = G / 131, pg = G - r * 131;
      int se = (pg << 3) - 17 - r;
      se = se < 0 ? 0 : (se > 1016 ? 1016 : se);
      gload16(revh + se, (char*)Ktab + (size_t)(it * 256 + (tid & 0xFFC0)) * 16);
    }
  }
  asm volatile("s_waitcnt vmcnt(0)" ::: "memory");
  __syncthreads();

  int cc = lane & 15, g = lane >> 4;
  int wt = w << 7;                       // wave's t-base (128 rows)
  // A-frag byte addr: (cc&7)*2096 + 2*(511 - wt - m*16 + ks*32 + g*8 + 17) - 16*(cc>>3)
  const char* kbase = (const char*)Ktab + (cc & 7) * 2096 - ((cc >> 3) << 4)
                      + (g << 4) + 2 * (528 - wt);
  const char* ubase = (const char*)Ulds;
  int usw = (cc & 7) << 4;

  f32x4 acc[8][2];
#pragma unroll
  for (int m = 0; m < 8; ++m)
#pragma unroll
    for (int n = 0; n < 2; ++n) acc[m][n] = (f32x4){0.f, 0.f, 0.f, 0.f};

  bf16x8 A[8];
#define LDA(slot, m, ks) A[slot] = *(const bf16x8*)(kbase - (m) * 32 + (ks) * 64)
  LDA(0, 0, 0); LDA(1, 1, 0); LDA(2, 2, 0); LDA(3, 3, 0);
  LDA(4, 4, 0); LDA(5, 5, 0); LDA(6, 6, 0); LDA(7, 7, 0);
#pragma unroll
  for (int ks = 0; ks < 16; ++ks) {
    if (ks > 0) {
      LDA((0 - 2 * ks) & 7, 0, ks);
      LDA((1 - 2 * ks) & 7, 1, ks);
    }
    int ub = ((ks << 6) + (g << 4)) ^ usw;
    bf16x8 B0 = *(const bf16x8*)(ubase + cc * 1024 + ub);
    bf16x8 B1 = *(const bf16x8*)(ubase + (16 + cc) * 1024 + ub);
#pragma unroll
    for (int m = 0; m < 8; ++m) {
      acc[m][0] = __builtin_amdgcn_mfma_f32_16x16x32_bf16(
          A[(m - 2 * ks) & 7], B0, acc[m][0], 0, 0, 0);
      acc[m][1] = __builtin_amdgcn_mfma_f32_16x16x32_bf16(
          A[(m - 2 * ks) & 7], B1, acc[m][1], 0, 0, 0);
    }
  }
#undef LDA

  // epilogue: y = acc + D*u; gelu(tanh) = y / (1 + exp2(-(c1*y + c3*y^3)))
  float dh = Dv[h];
  const float c1 = 2.3021181306612f, c3 = 0.1029392186f;
#pragma unroll
  for (int n = 0; n < 2; ++n) {
    int b = (n << 4) + cc;
    const char* up = (const char*)Ulds + b * 1024;
#pragma unroll
    for (int m = 0; m < 8; ++m) {
      int t0 = wt + (m << 4) + (g << 2);
      u16x4 uq = *(const u16x4*)(up + ((t0 << 1) ^ usw));
      float4 o;
#pragma unroll
      for (int r = 0; r < 4; ++r) {
        float y = acc[m][n][r] + dh * bf2f(uq[r]);
        float e = __builtin_amdgcn_exp2f(-(c1 * y + c3 * y * y * y));
        float gg = y * __builtin_amdgcn_rcpf(1.f + e);
        ((float*)&o)[r] = gg;
      }
      *(float4*)(Yc + (((size_t)b * HH + h) << 9) + t0) = o;
    }
  }
}

// ---------------------------------------------------------------------------
// [B,H,L] fp32 -> [B,L,H] bf16  (feeds GEMM)
// ---------------------------------------------------------------------------
__global__ __launch_bounds__(256) void t2bf_kernel(
    const float* __restrict__ U, ushort* __restrict__ Ybf) {
  __shared__ float tile[32][33];
  int b = blockIdx.z;
  int l0 = blockIdx.x << 5, h0 = blockIdx.y << 5;
  int tx = threadIdx.x, ty = threadIdx.y;
#pragma unroll
  for (int k = 0; k < 4; ++k)
    tile[ty + 8 * k][tx] = U[((size_t)b * HH + h0 + ty + 8 * k) * LL + l0 + tx];
  __syncthreads();
#pragma unroll
  for (int k = 0; k < 4; ++k)
    Ybf[((size_t)b * LL + l0 + ty + 8 * k) * HH + h0 + tx] = f2bf(tile[tx][ty + 8 * k]);
}

// ---------------------------------------------------------------------------
// bf16 MFMA GEMM (unchanged from round 3): G[b,l,o] = Ybf[b,l,:]*Wbf[o,:]+bias
// ---------------------------------------------------------------------------
__global__ __launch_bounds__(256) void gemm_kernel(
    const ushort* __restrict__ Ybf, const ushort* __restrict__ Wbf,
    const float* __restrict__ bias, float* __restrict__ G) {
  __shared__ ushort As[128 * 64];
  __shared__ ushort Bs[128 * 64];
  int tid = threadIdx.x;
  int wv = tid >> 6, lane = tid & 63;
  int wm = wv >> 1, wn = wv & 1;
  int b  = blockIdx.y >> 2;
  int l0 = (blockIdx.y & 3) << 7;
  int o0 = blockIdx.x << 7;

  int swz8 = (((lane & 7) ^ (lane >> 3)) << 3);
  int rsub = (lane >> 3);
  size_t arow0 = (size_t)(b * LL + l0 + wv * 32 + rsub) * HH;
  size_t brow0 = (size_t)(o0 + wv * 32 + rsub) * HH;
  char* Adst = (char*)As + wv * 4096;
  char* Bdst = (char*)Bs + wv * 4096;

  f32x4 acc[4][4];
#pragma unroll
  for (int i = 0; i < 4; ++i)
#pragma unroll
    for (int j = 0; j < 4; ++j) acc[i][j] = (f32x4){0.f, 0.f, 0.f, 0.f};

  for (int kt = 0; kt < HH / 64; ++kt) {
    int h0 = kt * 64;
#pragma unroll
    for (int i = 0; i < 4; ++i) {
      gload16(Ybf + arow0 + (size_t)i * 8 * HH + h0 + swz8, Adst + i * 1024);
      gload16(Wbf + brow0 + (size_t)i * 8 * HH + h0 + swz8, Bdst + i * 1024);
    }
    __syncthreads();

    bf16x8 af[4][2], bfr[4][2];
#pragma unroll
    for (int mi = 0; mi < 4; ++mi) {
      int m = wm * 64 + mi * 16 + (lane & 15);
#pragma unroll
      for (int kk = 0; kk < 2; ++kk) {
        int off = m * 128 + ((((lane >> 4) << 4) + (kk << 6)) ^ ((lane & 7) << 4));
        af[mi][kk] = *(const bf16x8*)((const char*)As + off);
      }
    }
#pragma unroll
    for (int ni = 0; ni < 4; ++ni) {
      int n = wn * 64 + ni * 16 + (lane & 15);
#pragma unroll
      for (int kk = 0; kk < 2; ++kk) {
        int off = n * 128 + ((((lane >> 4) << 4) + (kk << 6)) ^ ((lane & 7) << 4));
        bfr[ni][kk] = *(const bf16x8*)((const char*)Bs + off);
      }
    }
#pragma unroll
    for (int kk = 0; kk < 2; ++kk)
#pragma unroll
      for (int mi = 0; mi < 4; ++mi)
#pragma unroll
        for (int ni = 0; ni < 4; ++ni)
          acc[mi][ni] = __builtin_amdgcn_mfma_f32_16x16x32_bf16(
              af[mi][kk], bfr[ni][kk], acc[mi][ni], 0, 0, 0);
    __syncthreads();
  }

#pragma unroll
  for (int ni = 0; ni < 4; ++ni) {
    int n_g = o0 + wn * 64 + ni * 16 + (lane & 15);
    float bv = bias[n_g];
#pragma unroll
    for (int mi = 0; mi < 4; ++mi) {
      int m_g = l0 + wm * 64 + mi * 16 + ((lane >> 4) << 2);
      float* gp = G + ((size_t)b * LL + m_g) * HH + n_g;
#pragma unroll
      for (int j = 0; j < 4; ++j)
        gp[(size_t)j * HH] = acc[mi][ni][j] + bv;
    }
  }
}

// ---------------------------------------------------------------------------
extern "C" void kernel_launch(void* const* d_in, const int* in_sizes, int n_in,
                              void* d_out, int out_size, void* d_ws, size_t ws_size,
                              hipStream_t stream) {
  const float* x      = (const float*)d_in[0];
  const int*   mask   = (const int*)d_in[1];
  const float* ln1_w  = (const float*)d_in[2];
  const float* ln1_b  = (const float*)d_in[3];
  const float* log_dt = (const float*)d_in[4];
  const float* A_re   = (const float*)d_in[5];
  const float* A_im   = (const float*)d_in[6];
  const float* C_re   = (const float*)d_in[7];
  const float* C_im   = (const float*)d_in[8];
  const float* Dv     = (const float*)d_in[9];
  const float* Wout   = (const float*)d_in[10];
  const float* bout   = (const float*)d_in[11];
  const float* ln2_w  = (const float*)d_in[12];
  const float* ln2_b  = (const float*)d_in[13];
  float* out = (float*)d_out;

  // workspace: rev | Lbf (ln out bf16 / later Ybf) | Ubf | Wbf | buf1 (f32)
  ushort* rev  = (ushort*)d_ws;
  ushort* Lbf  = rev + (size_t)NLAYERS * HH * 1024;
  ushort* Ubf  = Lbf + (size_t)BB * LL * HH;
  ushort* Wbf  = Ubf + (size_t)BB * HH * LL;
  float*  buf1 = (float*)(Wbf + (size_t)NLAYERS * HH * HH);

  size_t xbytes = (size_t)BB * LL * HH * sizeof(float);
  hipMemcpyAsync(out, x, xbytes, hipMemcpyDeviceToDevice, stream);

  compute_k_kernel<<<NLAYERS * HH, 256, 0, stream>>>(log_dt, A_re, A_im, C_re, C_im, rev);
  wcast_kernel<<<(NLAYERS * HH * HH) / (256 * 8), 256, 0, stream>>>(Wout, Wbf);

  for (int il = 0; il < NLAYERS; ++il) {
    ln_mask_kernel<<<BB * LL / 4, 256, 0, stream>>>(
        out, ln1_w + il * HH, ln1_b + il * HH, mask, Lbf);
    transpose_bf_kernel<<<dim3(HH / 32, LL / 32, BB), dim3(32, 8), 0, stream>>>(Lbf, Ubf);
    conv_mfma_kernel<<<HH, 256, 0, stream>>>(
        Ubf, rev + (size_t)il * HH * 1024, Dv + il * HH, buf1);
    t2bf_kernel<<<dim3(LL / 32, HH / 32, BB), dim3(32, 8), 0, stream>>>(buf1, Lbf);
    gemm_kernel<<<dim3(HH / 128, BB * LL / 128), 256, 0, stream>>>(
        Lbf, Wbf + (size_t)il * HH * HH, bout + il * HH, buf1);
    ln_residual_kernel<<<BB * LL / 4, 256, 0, stream>>>(
        buf1, ln2_w + il * HH, ln2_b + il * HH, out);
  }
}

// Round 5
// 564.058 us; speedup vs baseline: 4.4467x; 1.2620x over previous
//
#include <hip/hip_runtime.h>
#include <math.h>

#define BB 32
#define LL 512
#define HH 768
#define NN 64
#define NLAYERS 4

typedef unsigned short ushort;
typedef __attribute__((ext_vector_type(8))) short bf16x8;
typedef __attribute__((ext_vector_type(4))) float f32x4;
typedef __attribute__((ext_vector_type(4))) ushort u16x4;

static __device__ __forceinline__ ushort f2bf(float f) {
  union { float f; unsigned u; } v; v.f = f;
  unsigned r = (v.u + 0x7FFF + ((v.u >> 16) & 1)) >> 16;   // RNE
  return (ushort)r;
}
static __device__ __forceinline__ float bf2f(ushort u) {
  union { unsigned u; float f; } v; v.u = ((unsigned)u) << 16; return v.f;
}
static __device__ __forceinline__ void gload16(const void* g, void* l) {
  __builtin_amdgcn_global_load_lds(
      (const __attribute__((address_space(1))) unsigned int*)g,
      (__attribute__((address_space(3))) unsigned int*)l, 16, 0, 0);
}
static __device__ __forceinline__ float hw_sin(float f) {
#if __has_builtin(__builtin_amdgcn_sinf)
  return __builtin_amdgcn_sinf(f);
#else
  float r; asm("v_sin_f32 %0, %1" : "=v"(r) : "v"(f)); return r;
#endif
}
static __device__ __forceinline__ float hw_cos(float f) {
#if __has_builtin(__builtin_amdgcn_cosf)
  return __builtin_amdgcn_cosf(f);
#else
  float r; asm("v_cos_f32 %0, %1" : "=v"(r) : "v"(f)); return r;
#endif
}

// ---------------------------------------------------------------------------
// compute_k v2: recurrence-based. rev[i] = bf16(Kb[1023-i]),
// Kb[512+d]=K0[d], Kb[511-m]=K1[m];  y[t] = sum_tau u[tau]*Kb[512+t-tau].
// One wave per (il,h). Phase 0 (lane=n): q=e^{dtA}, powers q^{8*2^j}, weights.
// Phase 1 (lane=t, l in [8t,8t+8)): v0=q^{8t} by binary exponentiation, then
// 8 recurrence steps; K = Re(cw * v) accumulated over n.
// ---------------------------------------------------------------------------
__global__ __launch_bounds__(256) void compute_k_kernel(
    const float* __restrict__ log_dt, const float* __restrict__ A_re,
    const float* __restrict__ A_im, const float* __restrict__ C_re,
    const float* __restrict__ C_im, ushort* __restrict__ rev) {
  __shared__ float4 cons[4][64][5];
  int wid = threadIdx.x >> 6, lane = threadIdx.x & 63;
  int blk = blockIdx.x * 4 + wid;          // il*HH + h
  int il = blk / HH, h = blk - il * HH;
  {
    int n = lane;
    float dt = expf(log_dt[blk]);
    float a_re = -expf(A_re[(size_t)blk * NN + n]);
    float a_im = A_im[(size_t)blk * NN + n];
    float er = dt * a_re, ei = dt * a_im;
    float ea = __builtin_amdgcn_exp2f(er * 1.4426950408889634f);
    float fr = ei * 0.15915494309189535f;   // revolutions
    fr = fr - floorf(fr);
    float sv = hw_sin(fr), cv = hw_cos(fr);
    float qr = ea * cv, qi = ea * sv;
    float e1r = qr - 1.f, e1i = qi;
    float den = a_re * a_re + a_im * a_im;
    float wr = (e1r * a_re + e1i * a_im) / den;
    float wi = (e1i * a_re - e1r * a_im) / den;
    size_t c0 = ((size_t)(il * 2 + 0) * HH + h) * NN + n;
    size_t c1 = ((size_t)(il * 2 + 1) * HH + h) * NN + n;
    float c0r = C_re[c0], c0i = C_im[c0];
    float c1r = C_re[c1], c1i = C_im[c1];
    float c0wr = 2.f * (c0r * wr - c0i * wi), c0wi = 2.f * (c0r * wi + c0i * wr);
    float c1wr = 2.f * (c1r * wr - c1i * wi), c1wi = 2.f * (c1r * wi + c1i * wr);
    float pr = qr, pi = qi;
    float P[6][2];
#pragma unroll
    for (int j = 0; j < 8; ++j) {
      float nr = pr * pr - pi * pi, ni = 2.f * pr * pi;
      pr = nr; pi = ni;                      // q^(2^(j+1))
      if (j >= 2) { P[j - 2][0] = pr; P[j - 2][1] = pi; }   // q^8 .. q^256
    }
    cons[wid][n][0] = make_float4(qr, qi, c0wr, c0wi);
    cons[wid][n][1] = make_float4(c1wr, c1wi, P[0][0], P[0][1]);
    cons[wid][n][2] = make_float4(P[1][0], P[1][1], P[2][0], P[2][1]);
    cons[wid][n][3] = make_float4(P[3][0], P[3][1], P[4][0], P[4][1]);
    cons[wid][n][4] = make_float4(P[5][0], P[5][1], 0.f, 0.f);
  }
  __syncthreads();
  int t = lane;
  float k0[8], k1[8];
#pragma unroll
  for (int s = 0; s < 8; ++s) { k0[s] = 0.f; k1[s] = 0.f; }
  for (int n = 0; n < NN; ++n) {
    float4 A0 = cons[wid][n][0];
    float4 A1 = cons[wid][n][1];
    float4 A2 = cons[wid][n][2];
    float4 A3 = cons[wid][n][3];
    float4 A4 = cons[wid][n][4];
    float vr = 1.f, vi = 0.f;
#define MULIF(BIT, PR, PI) { bool c = (t & (BIT)) != 0;                       \
    float nr = vr * (PR) - vi * (PI), ni = vr * (PI) + vi * (PR);             \
    vr = c ? nr : vr; vi = c ? ni : vi; }
    MULIF(1,  A1.z, A1.w)
    MULIF(2,  A2.x, A2.y)
    MULIF(4,  A2.z, A2.w)
    MULIF(8,  A3.x, A3.y)
    MULIF(16, A3.z, A3.w)
    MULIF(32, A4.x, A4.y)
#undef MULIF
#pragma unroll
    for (int s = 0; s < 8; ++s) {
      k0[s] = fmaf(A0.z, vr, fmaf(-A0.w, vi, k0[s]));
      k1[s] = fmaf(A1.x, vr, fmaf(-A1.y, vi, k1[s]));
      float nr = vr * A0.x - vi * A0.y;
      float ni = vr * A0.y + vi * A0.x;
      vr = nr; vi = ni;
    }
  }
  ushort* row = rev + ((size_t)blk << 10);
  bf16x8 o0, o1;
#pragma unroll
  for (int i = 0; i < 8; ++i) {
    o0[i] = (short)f2bf(k0[7 - i]);   // rev[504-8t+i] = K0[8t+7-i]
    o1[i] = (short)f2bf(k1[i]);       // rev[512+8t+i] = K1[8t+i]
  }
  *(bf16x8*)(row + 504 - 8 * t) = o0;
  *(bf16x8*)(row + 512 + 8 * t) = o1;
}

// ---------------------------------------------------------------------------
// Wout fp32 -> bf16 (once)
// ---------------------------------------------------------------------------
__global__ __launch_bounds__(256) void wcast_kernel(
    const float* __restrict__ W, ushort* __restrict__ Wbf) {
  size_t i = ((size_t)blockIdx.x * 256 + threadIdx.x) * 8;
  float4 a = *(const float4*)&W[i];
  float4 c = *(const float4*)&W[i + 4];
  ushort o[8] = {f2bf(a.x), f2bf(a.y), f2bf(a.z), f2bf(a.w),
                 f2bf(c.x), f2bf(c.y), f2bf(c.z), f2bf(c.w)};
  *(bf16x8*)&Wbf[i] = *(bf16x8*)o;
}

// ---------------------------------------------------------------------------
// Fused LN1 * mask + transpose + bf16: X f32 [B,L,H] -> U bf16 [B,H,L]
// Block covers 32 l-rows; LDS tile [32 l][772 h-stride] bf16.
// ---------------------------------------------------------------------------
__global__ __launch_bounds__(256) void ln_t_kernel(
    const float* __restrict__ X, const float* __restrict__ w,
    const float* __restrict__ b, const int* __restrict__ mask,
    ushort* __restrict__ U) {
  __shared__ ushort tile[32][772];
  int bb = blockIdx.y;
  int l0 = blockIdx.x << 5;
  int wv = threadIdx.x >> 6, lane = threadIdx.x & 63;
  const float4* w4 = (const float4*)w;
  const float4* b4 = (const float4*)b;
  float4 WW[3], BV[3];
#pragma unroll
  for (int m = 0; m < 3; ++m) { WW[m] = w4[lane + 64 * m]; BV[m] = b4[lane + 64 * m]; }
#pragma unroll
  for (int i = 0; i < 8; ++i) {
    int r = (wv << 3) + i;
    size_t rowi = (size_t)bb * LL + l0 + r;
    const float4* xr = (const float4*)(X + rowi * HH);
    float4 v[3];
    float s = 0.f, s2 = 0.f;
#pragma unroll
    for (int m = 0; m < 3; ++m) {
      v[m] = xr[lane + 64 * m];
      s  += v[m].x + v[m].y + v[m].z + v[m].w;
      s2 += v[m].x * v[m].x + v[m].y * v[m].y + v[m].z * v[m].z + v[m].w * v[m].w;
    }
#pragma unroll
    for (int off = 32; off >= 1; off >>= 1) {
      s  += __shfl_xor(s, off);
      s2 += __shfl_xor(s2, off);
    }
    float mu  = s * (1.f / HH);
    float var = s2 * (1.f / HH) - mu * mu;
    float rs  = rsqrtf(var + 1e-5f);
    float mf  = (float)mask[rowi];
#pragma unroll
    for (int m = 0; m < 3; ++m) {
      u16x4 o;
      o.x = f2bf(((v[m].x - mu) * rs * WW[m].x + BV[m].x) * mf);
      o.y = f2bf(((v[m].y - mu) * rs * WW[m].y + BV[m].y) * mf);
      o.z = f2bf(((v[m].z - mu) * rs * WW[m].z + BV[m].z) * mf);
      o.w = f2bf(((v[m].w - mu) * rs * WW[m].w + BV[m].w) * mf);
      *(u16x4*)&tile[r][(lane + 64 * m) << 2] = o;
    }
  }
  __syncthreads();
#pragma unroll
  for (int it = 0; it < 3; ++it) {
    int h = it * 256 + threadIdx.x;
    ushort* dst = U + (((size_t)bb * HH + h) << 9) + l0;
#pragma unroll
    for (int c = 0; c < 4; ++c) {
      bf16x8 o;
#pragma unroll
      for (int j = 0; j < 8; ++j) o[j] = (short)tile[c * 8 + j][h];
      *(bf16x8*)(dst + (c << 3)) = o;
    }
  }
}

// ---------------------------------------------------------------------------
// LN2(G) + base -> out  (base = x for layer 0, out otherwise)
// ---------------------------------------------------------------------------
__global__ __launch_bounds__(256) void ln_res_kernel(
    const float* __restrict__ G, const float* __restrict__ w,
    const float* __restrict__ b, const float* __restrict__ base,
    float* __restrict__ out) {
  int wv = threadIdx.x >> 6, lane = threadIdx.x & 63;
  size_t r = (size_t)blockIdx.x * 4 + wv;
  const float4* gr = (const float4*)(G + r * HH);
  float4 v[3];
  float s = 0.f, s2 = 0.f;
#pragma unroll
  for (int m = 0; m < 3; ++m) {
    v[m] = gr[lane + 64 * m];
    s  += v[m].x + v[m].y + v[m].z + v[m].w;
    s2 += v[m].x * v[m].x + v[m].y * v[m].y + v[m].z * v[m].z + v[m].w * v[m].w;
  }
#pragma unroll
  for (int off = 32; off >= 1; off >>= 1) {
    s  += __shfl_xor(s, off);
    s2 += __shfl_xor(s2, off);
  }
  float mu  = s * (1.f / HH);
  float var = s2 * (1.f / HH) - mu * mu;
  float rs  = rsqrtf(var + 1e-5f);
  const float4* w4 = (const float4*)w;
  const float4* b4 = (const float4*)b;
  const float4* br = (const float4*)(base + r * HH);
  float4* xr = (float4*)(out + r * HH);
#pragma unroll
  for (int m = 0; m < 3; ++m) {
    float4 ww = w4[lane + 64 * m], bb = b4[lane + 64 * m];
    float4 xv = br[lane + 64 * m];
    xv.x += (v[m].x - mu) * rs * ww.x + bb.x;
    xv.y += (v[m].y - mu) * rs * ww.y + bb.y;
    xv.z += (v[m].z - mu) * rs * ww.z + bb.z;
    xv.w += (v[m].w - mu) * rs * ww.w + bb.w;
    xr[lane + 64 * m] = xv;
  }
}

// ---------------------------------------------------------------------------
// MFMA Toeplitz conv + D*u + gelu.  One wg per h.  Output bf16 [B,H,L].
// ---------------------------------------------------------------------------
__global__ __launch_bounds__(256) void conv_mfma_kernel(
    const ushort* __restrict__ Ubf, const ushort* __restrict__ rev,
    const float* __restrict__ Dv, ushort* __restrict__ Cbf) {
  __shared__ ushort Ulds[32 * 512];    // 32 KB
  __shared__ ushort Ktab[8 * 1048];    // 16.4 KB
  int tid = threadIdx.x;
  int w = tid >> 6, lane = tid & 63;
  int h = blockIdx.x;

#pragma unroll
  for (int it = 0; it < 8; ++it) {
    int G = it * 256 + tid;
    int b = G >> 6, cg = G & 63;
    gload16(Ubf + (((size_t)b * HH + h) << 9) + ((cg ^ (b & 7)) << 3),
            (char*)Ulds + (size_t)(it * 256 + (tid & 0xFFC0)) * 16);
  }
  const ushort* revh = rev + ((size_t)h << 10);
#pragma unroll
  for (int it = 0; it < 5; ++it) {
    int G = it * 256 + tid;
    if (G < 1048) {
      int r = G / 131, pg = G - r * 131;
      int se = (pg << 3) - 17 - r;
      se = se < 0 ? 0 : (se > 1016 ? 1016 : se);
      gload16(revh + se, (char*)Ktab + (size_t)(it * 256 + (tid & 0xFFC0)) * 16);
    }
  }
  asm volatile("s_waitcnt vmcnt(0)" ::: "memory");
  __syncthreads();

  int cc = lane & 15, g = lane >> 4;
  int wt = w << 7;
  const char* kbase = (const char*)Ktab + (cc & 7) * 2096 - ((cc >> 3) << 4)
                      + (g << 4) + 2 * (528 - wt);
  const char* ubase = (const char*)Ulds;
  int usw = (cc & 7) << 4;

  f32x4 acc[8][2];
#pragma unroll
  for (int m = 0; m < 8; ++m)
#pragma unroll
    for (int n = 0; n < 2; ++n) acc[m][n] = (f32x4){0.f, 0.f, 0.f, 0.f};

  bf16x8 A[8];
#define LDA(slot, m, ks) A[slot] = *(const bf16x8*)(kbase - (m) * 32 + (ks) * 64)
  LDA(0, 0, 0); LDA(1, 1, 0); LDA(2, 2, 0); LDA(3, 3, 0);
  LDA(4, 4, 0); LDA(5, 5, 0); LDA(6, 6, 0); LDA(7, 7, 0);
#pragma unroll
  for (int ks = 0; ks < 16; ++ks) {
    if (ks > 0) {
      LDA((0 - 2 * ks) & 7, 0, ks);
      LDA((1 - 2 * ks) & 7, 1, ks);
    }
    int ub = ((ks << 6) + (g << 4)) ^ usw;
    bf16x8 B0 = *(const bf16x8*)(ubase + cc * 1024 + ub);
    bf16x8 B1 = *(const bf16x8*)(ubase + (16 + cc) * 1024 + ub);
#pragma unroll
    for (int m = 0; m < 8; ++m) {
      acc[m][0] = __builtin_amdgcn_mfma_f32_16x16x32_bf16(
          A[(m - 2 * ks) & 7], B0, acc[m][0], 0, 0, 0);
      acc[m][1] = __builtin_amdgcn_mfma_f32_16x16x32_bf16(
          A[(m - 2 * ks) & 7], B1, acc[m][1], 0, 0, 0);
    }
  }
#undef LDA

  float dh = Dv[h];
  const float c1 = 2.3021181306612f, c3 = 0.1029392186f;
#pragma unroll
  for (int n = 0; n < 2; ++n) {
    int b = (n << 4) + cc;
    const char* up = (const char*)Ulds + b * 1024;
#pragma unroll
    for (int m = 0; m < 8; ++m) {
      int t0 = wt + (m << 4) + (g << 2);
      u16x4 uq = *(const u16x4*)(up + ((t0 << 1) ^ usw));
      u16x4 o;
#pragma unroll
      for (int r = 0; r < 4; ++r) {
        float y = acc[m][n][r] + dh * bf2f(uq[r]);
        float e = __builtin_amdgcn_exp2f(-(c1 * y + c3 * y * y * y));
        float gg = y * __builtin_amdgcn_rcpf(1.f + e);
        o[r] = f2bf(gg);
      }
      *(u16x4*)(Cbf + (((size_t)b * HH + h) << 9) + t0) = o;
    }
  }
}

// ---------------------------------------------------------------------------
// bf16 [B,H,L] -> bf16 [B,L,H]
// ---------------------------------------------------------------------------
__global__ __launch_bounds__(256) void t2bf_bf_kernel(
    const ushort* __restrict__ C, ushort* __restrict__ Y) {
  __shared__ ushort tile[32][34];
  int b = blockIdx.z;
  int h0 = blockIdx.x << 5, l0 = blockIdx.y << 5;
  int tx = threadIdx.x, ty = threadIdx.y;
#pragma unroll
  for (int k = 0; k < 4; ++k)
    tile[ty + 8 * k][tx] = C[(((size_t)b * HH + h0 + ty + 8 * k) << 9) + l0 + tx];
  __syncthreads();
#pragma unroll
  for (int k = 0; k < 4; ++k)
    Y[((size_t)b * LL + l0 + ty + 8 * k) * HH + h0 + tx] = tile[tx][ty + 8 * k];
}

// ---------------------------------------------------------------------------
// bf16 MFMA GEMM (unchanged): G[b,l,o] = Ybf[b,l,:]*Wbf[o,:]+bias
// ---------------------------------------------------------------------------
__global__ __launch_bounds__(256) void gemm_kernel(
    const ushort* __restrict__ Ybf, const ushort* __restrict__ Wbf,
    const float* __restrict__ bias, float* __restrict__ G) {
  __shared__ ushort As[128 * 64];
  __shared__ ushort Bs[128 * 64];
  int tid = threadIdx.x;
  int wv = tid >> 6, lane = tid & 63;
  int wm = wv >> 1, wn = wv & 1;
  int b  = blockIdx.y >> 2;
  int l0 = (blockIdx.y & 3) << 7;
  int o0 = blockIdx.x << 7;

  int swz8 = (((lane & 7) ^ (lane >> 3)) << 3);
  int rsub = (lane >> 3);
  size_t arow0 = (size_t)(b * LL + l0 + wv * 32 + rsub) * HH;
  size_t brow0 = (size_t)(o0 + wv * 32 + rsub) * HH;
  char* Adst = (char*)As + wv * 4096;
  char* Bdst = (char*)Bs + wv * 4096;

  f32x4 acc[4][4];
#pragma unroll
  for (int i = 0; i < 4; ++i)
#pragma unroll
    for (int j = 0; j < 4; ++j) acc[i][j] = (f32x4){0.f, 0.f, 0.f, 0.f};

  for (int kt = 0; kt < HH / 64; ++kt) {
    int h0 = kt * 64;
#pragma unroll
    for (int i = 0; i < 4; ++i) {
      gload16(Ybf + arow0 + (size_t)i * 8 * HH + h0 + swz8, Adst + i * 1024);
      gload16(Wbf + brow0 + (size_t)i * 8 * HH + h0 + swz8, Bdst + i * 1024);
    }
    __syncthreads();

    bf16x8 af[4][2], bfr[4][2];
#pragma unroll
    for (int mi = 0; mi < 4; ++mi) {
      int m = wm * 64 + mi * 16 + (lane & 15);
#pragma unroll
      for (int kk = 0; kk < 2; ++kk) {
        int off = m * 128 + ((((lane >> 4) << 4) + (kk << 6)) ^ ((lane & 7) << 4));
        af[mi][kk] = *(const bf16x8*)((const char*)As + off);
      }
    }
#pragma unroll
    for (int ni = 0; ni < 4; ++ni) {
      int n = wn * 64 + ni * 16 + (lane & 15);
#pragma unroll
      for (int kk = 0; kk < 2; ++kk) {
        int off = n * 128 + ((((lane >> 4) << 4) + (kk << 6)) ^ ((lane & 7) << 4));
        bfr[ni][kk] = *(const bf16x8*)((const char*)Bs + off);
      }
    }
#pragma unroll
    for (int kk = 0; kk < 2; ++kk)
#pragma unroll
      for (int mi = 0; mi < 4; ++mi)
#pragma unroll
        for (int ni = 0; ni < 4; ++ni)
          acc[mi][ni] = __builtin_amdgcn_mfma_f32_16x16x32_bf16(
              af[mi][kk], bfr[ni][kk], acc[mi][ni], 0, 0, 0);
    __syncthreads();
  }

#pragma unroll
  for (int ni = 0; ni < 4; ++ni) {
    int n_g = o0 + wn * 64 + ni * 16 + (lane & 15);
    float bv = bias[n_g];
#pragma unroll
    for (int mi = 0; mi < 4; ++mi) {
      int m_g = l0 + wm * 64 + mi * 16 + ((lane >> 4) << 2);
      float* gp = G + ((size_t)b * LL + m_g) * HH + n_g;
#pragma unroll
      for (int j = 0; j < 4; ++j)
        gp[(size_t)j * HH] = acc[mi][ni][j] + bv;
    }
  }
}

// ---------------------------------------------------------------------------
extern "C" void kernel_launch(void* const* d_in, const int* in_sizes, int n_in,
                              void* d_out, int out_size, void* d_ws, size_t ws_size,
                              hipStream_t stream) {
  const float* x      = (const float*)d_in[0];
  const int*   mask   = (const int*)d_in[1];
  const float* ln1_w  = (const float*)d_in[2];
  const float* ln1_b  = (const float*)d_in[3];
  const float* log_dt = (const float*)d_in[4];
  const float* A_re   = (const float*)d_in[5];
  const float* A_im   = (const float*)d_in[6];
  const float* C_re   = (const float*)d_in[7];
  const float* C_im   = (const float*)d_in[8];
  const float* Dv     = (const float*)d_in[9];
  const float* Wout   = (const float*)d_in[10];
  const float* bout   = (const float*)d_in[11];
  const float* ln2_w  = (const float*)d_in[12];
  const float* ln2_b  = (const float*)d_in[13];
  float* out = (float*)d_out;

  // ws: rev | Ubf (also reused as Ybf) | Cbf | Wbf | Gf
  ushort* rev  = (ushort*)d_ws;                               // NL*H*1024
  ushort* Ubf  = rev + (size_t)NLAYERS * HH * 1024;           // B*H*L
  ushort* Cbf  = Ubf + (size_t)BB * HH * LL;                  // B*H*L
  ushort* Wbf  = Cbf + (size_t)BB * HH * LL;                  // NL*H*H
  float*  Gf   = (float*)(Wbf + (size_t)NLAYERS * HH * HH);   // B*L*H f32
  ushort* Ybf  = Ubf;   // safe reuse: conv consumed Ubf before t2bf writes it

  compute_k_kernel<<<NLAYERS * HH / 4, 256, 0, stream>>>(
      log_dt, A_re, A_im, C_re, C_im, rev);
  wcast_kernel<<<(NLAYERS * HH * HH) / (256 * 8), 256, 0, stream>>>(Wout, Wbf);

  for (int il = 0; il < NLAYERS; ++il) {
    const float* src = (il == 0) ? x : out;
    ln_t_kernel<<<dim3(LL / 32, BB), 256, 0, stream>>>(
        src, ln1_w + il * HH, ln1_b + il * HH, mask, Ubf);
    conv_mfma_kernel<<<HH, 256, 0, stream>>>(
        Ubf, rev + (size_t)il * HH * 1024, Dv + il * HH, Cbf);
    t2bf_bf_kernel<<<dim3(HH / 32, LL / 32, BB), dim3(32, 8), 0, stream>>>(Cbf, Ybf);
    gemm_kernel<<<dim3(HH / 128, BB * LL / 128), 256, 0, stream>>>(
        Ybf, Wbf + (size_t)il * HH * HH, bout + il * HH, Gf);
    ln_res_kernel<<<BB * LL / 4, 256, 0, stream>>>(
        Gf, ln2_w + il * HH, ln2_b + il * HH, src, out);
  }
}

// Round 6
// 526.608 us; speedup vs baseline: 4.7630x; 1.0711x over previous
//
#include <hip/hip_runtime.h>
#include <math.h>

#define BB 32
#define LL 512
#define HH 768
#define NN 64
#define NLAYERS 4

typedef unsigned short ushort;
typedef __attribute__((ext_vector_type(8))) short bf16x8;
typedef __attribute__((ext_vector_type(4))) float f32x4;
typedef __attribute__((ext_vector_type(4))) ushort u16x4;

static __device__ __forceinline__ ushort f2bf(float f) {
  union { float f; unsigned u; } v; v.f = f;
  unsigned r = (v.u + 0x7FFF + ((v.u >> 16) & 1)) >> 16;   // RNE
  return (ushort)r;
}
static __device__ __forceinline__ float bf2f(ushort u) {
  union { unsigned u; float f; } v; v.u = ((unsigned)u) << 16; return v.f;
}
static __device__ __forceinline__ void gload16(const void* g, void* l) {
  __builtin_amdgcn_global_load_lds(
      (const __attribute__((address_space(1))) unsigned int*)g,
      (__attribute__((address_space(3))) unsigned int*)l, 16, 0, 0);
}
static __device__ __forceinline__ float hw_sin(float f) {
  float r; asm("v_sin_f32 %0, %1" : "=v"(r) : "v"(f)); return r;
}
static __device__ __forceinline__ float hw_cos(float f) {
  float r; asm("v_cos_f32 %0, %1" : "=v"(r) : "v"(f)); return r;
}

// ---------------------------------------------------------------------------
// compute_k v3: recurrence-based, n-split across 2 waves per (il,h).
// rev[i] = bf16(Kb[1023-i]); Kb[512+d]=K0[d], Kb[511-m]=K1[m].
// wg of 256 = 4 waves handles 2 (il,h) pairs; waves (2p, 2p+1) split n 0..31 /
// 32..63, partials reduced through padded LDS.
// ---------------------------------------------------------------------------
__global__ __launch_bounds__(256) void compute_k_kernel(
    const float* __restrict__ log_dt, const float* __restrict__ A_re,
    const float* __restrict__ A_im, const float* __restrict__ C_re,
    const float* __restrict__ C_im, ushort* __restrict__ rev) {
  __shared__ float4 cons[2][64][5];
  __shared__ float red[2][64][17];
  int wid = threadIdx.x >> 6, lane = threadIdx.x & 63;
  int p = wid >> 1, nh = wid & 1;
  int blk = blockIdx.x * 2 + p;            // il*HH + h
  int il = blk / HH, h = blk - il * HH;
  if (lane < 32) {
    int n = nh * 32 + lane;
    float dt = expf(log_dt[blk]);
    float a_re = -expf(A_re[(size_t)blk * NN + n]);
    float a_im = A_im[(size_t)blk * NN + n];
    float er = dt * a_re, ei = dt * a_im;
    float ea = __builtin_amdgcn_exp2f(er * 1.4426950408889634f);
    float fr = ei * 0.15915494309189535f;   // revolutions
    fr = fr - floorf(fr);
    float sv = hw_sin(fr), cv = hw_cos(fr);
    float qr = ea * cv, qi = ea * sv;
    float e1r = qr - 1.f, e1i = qi;
    float den = a_re * a_re + a_im * a_im;
    float wr = (e1r * a_re + e1i * a_im) / den;
    float wi = (e1i * a_re - e1r * a_im) / den;
    size_t c0 = ((size_t)(il * 2 + 0) * HH + h) * NN + n;
    size_t c1 = ((size_t)(il * 2 + 1) * HH + h) * NN + n;
    float c0r = C_re[c0], c0i = C_im[c0];
    float c1r = C_re[c1], c1i = C_im[c1];
    float c0wr = 2.f * (c0r * wr - c0i * wi), c0wi = 2.f * (c0r * wi + c0i * wr);
    float c1wr = 2.f * (c1r * wr - c1i * wi), c1wi = 2.f * (c1r * wi + c1i * wr);
    float pr = qr, pi = qi;
    float P[6][2];
#pragma unroll
    for (int j = 0; j < 8; ++j) {
      float nr = pr * pr - pi * pi, ni = 2.f * pr * pi;
      pr = nr; pi = ni;
      if (j >= 2) { P[j - 2][0] = pr; P[j - 2][1] = pi; }
    }
    cons[p][n][0] = make_float4(qr, qi, c0wr, c0wi);
    cons[p][n][1] = make_float4(c1wr, c1wi, P[0][0], P[0][1]);
    cons[p][n][2] = make_float4(P[1][0], P[1][1], P[2][0], P[2][1]);
    cons[p][n][3] = make_float4(P[3][0], P[3][1], P[4][0], P[4][1]);
    cons[p][n][4] = make_float4(P[5][0], P[5][1], 0.f, 0.f);
  }
  __syncthreads();
  int t = lane;
  float k0[8], k1[8];
#pragma unroll
  for (int s = 0; s < 8; ++s) { k0[s] = 0.f; k1[s] = 0.f; }
  for (int nn = 0; nn < 32; ++nn) {
    int n = nh * 32 + nn;
    float4 A0 = cons[p][n][0];
    float4 A1 = cons[p][n][1];
    float4 A2 = cons[p][n][2];
    float4 A3 = cons[p][n][3];
    float4 A4 = cons[p][n][4];
    float vr = 1.f, vi = 0.f;
#define MULIF(BIT, PR, PI) { bool c = (t & (BIT)) != 0;                       \
    float nr = vr * (PR) - vi * (PI), ni = vr * (PI) + vi * (PR);             \
    vr = c ? nr : vr; vi = c ? ni : vi; }
    MULIF(1,  A1.z, A1.w)
    MULIF(2,  A2.x, A2.y)
    MULIF(4,  A2.z, A2.w)
    MULIF(8,  A3.x, A3.y)
    MULIF(16, A3.z, A3.w)
    MULIF(32, A4.x, A4.y)
#undef MULIF
#pragma unroll
    for (int s = 0; s < 8; ++s) {
      k0[s] = fmaf(A0.z, vr, fmaf(-A0.w, vi, k0[s]));
      k1[s] = fmaf(A1.x, vr, fmaf(-A1.y, vi, k1[s]));
      float nr = vr * A0.x - vi * A0.y;
      float ni = vr * A0.y + vi * A0.x;
      vr = nr; vi = ni;
    }
  }
  if (nh == 1) {
#pragma unroll
    for (int s = 0; s < 8; ++s) {
      red[p][lane][s] = k0[s];
      red[p][lane][8 + s] = k1[s];
    }
  }
  __syncthreads();
  if (nh == 0) {
#pragma unroll
    for (int s = 0; s < 8; ++s) {
      k0[s] += red[p][lane][s];
      k1[s] += red[p][lane][8 + s];
    }
    ushort* row = rev + ((size_t)blk << 10);
    bf16x8 o0, o1;
#pragma unroll
    for (int i = 0; i < 8; ++i) {
      o0[i] = (short)f2bf(k0[7 - i]);   // rev[504-8t+i] = K0[8t+7-i]
      o1[i] = (short)f2bf(k1[i]);       // rev[512+8t+i] = K1[8t+i]
    }
    *(bf16x8*)(row + 504 - 8 * t) = o0;
    *(bf16x8*)(row + 512 + 8 * t) = o1;
  }
}

// ---------------------------------------------------------------------------
// Wout fp32 -> bf16 (once)
// ---------------------------------------------------------------------------
__global__ __launch_bounds__(256) void wcast_kernel(
    const float* __restrict__ W, ushort* __restrict__ Wbf) {
  size_t i = ((size_t)blockIdx.x * 256 + threadIdx.x) * 8;
  float4 a = *(const float4*)&W[i];
  float4 c = *(const float4*)&W[i + 4];
  ushort o[8] = {f2bf(a.x), f2bf(a.y), f2bf(a.z), f2bf(a.w),
                 f2bf(c.x), f2bf(c.y), f2bf(c.z), f2bf(c.w)};
  *(bf16x8*)&Wbf[i] = *(bf16x8*)o;
}

// ---------------------------------------------------------------------------
// Fused LN1 * mask + transpose + bf16: X f32 [B,L,H] -> U bf16 [B,H,L]
// (layer 0 only)
// ---------------------------------------------------------------------------
__global__ __launch_bounds__(256) void ln_t_kernel(
    const float* __restrict__ X, const float* __restrict__ w,
    const float* __restrict__ b, const int* __restrict__ mask,
    ushort* __restrict__ U) {
  __shared__ ushort tile[32][772];
  int bb = blockIdx.y;
  int l0 = blockIdx.x << 5;
  int wv = threadIdx.x >> 6, lane = threadIdx.x & 63;
  const float4* w4 = (const float4*)w;
  const float4* b4 = (const float4*)b;
  float4 WW[3], BV[3];
#pragma unroll
  for (int m = 0; m < 3; ++m) { WW[m] = w4[lane + 64 * m]; BV[m] = b4[lane + 64 * m]; }
#pragma unroll
  for (int i = 0; i < 8; ++i) {
    int r = (wv << 3) + i;
    size_t rowi = (size_t)bb * LL + l0 + r;
    const float4* xr = (const float4*)(X + rowi * HH);
    float4 v[3];
    float s = 0.f, s2 = 0.f;
#pragma unroll
    for (int m = 0; m < 3; ++m) {
      v[m] = xr[lane + 64 * m];
      s  += v[m].x + v[m].y + v[m].z + v[m].w;
      s2 += v[m].x * v[m].x + v[m].y * v[m].y + v[m].z * v[m].z + v[m].w * v[m].w;
    }
#pragma unroll
    for (int off = 32; off >= 1; off >>= 1) {
      s  += __shfl_xor(s, off);
      s2 += __shfl_xor(s2, off);
    }
    float mu  = s * (1.f / HH);
    float var = s2 * (1.f / HH) - mu * mu;
    float rs  = rsqrtf(var + 1e-5f);
    float mf  = (float)mask[rowi];
#pragma unroll
    for (int m = 0; m < 3; ++m) {
      u16x4 o;
      o.x = f2bf(((v[m].x - mu) * rs * WW[m].x + BV[m].x) * mf);
      o.y = f2bf(((v[m].y - mu) * rs * WW[m].y + BV[m].y) * mf);
      o.z = f2bf(((v[m].z - mu) * rs * WW[m].z + BV[m].z) * mf);
      o.w = f2bf(((v[m].w - mu) * rs * WW[m].w + BV[m].w) * mf);
      *(u16x4*)&tile[r][(lane + 64 * m) << 2] = o;
    }
  }
  __syncthreads();
#pragma unroll
  for (int it = 0; it < 3; ++it) {
    int h = it * 256 + threadIdx.x;
    ushort* dst = U + (((size_t)bb * HH + h) << 9) + l0;
#pragma unroll
    for (int c = 0; c < 4; ++c) {
      bf16x8 o;
#pragma unroll
      for (int j = 0; j < 8; ++j) o[j] = (short)tile[c * 8 + j][h];
      *(bf16x8*)(dst + (c << 3)) = o;
    }
  }
}

// ---------------------------------------------------------------------------
// Fused: out = base + LN2(Gbf);  U = transpose(bf16(LN1(out)*mask))
// (layer boundary: closes layer il, opens layer il+1)
// ---------------------------------------------------------------------------
__global__ __launch_bounds__(256) void res_lnt_kernel(
    const ushort* __restrict__ Gbf, const float* __restrict__ w2,
    const float* __restrict__ b2, const float* __restrict__ base,
    float* __restrict__ out, const int* __restrict__ mask,
    const float* __restrict__ w1, const float* __restrict__ b1,
    ushort* __restrict__ U) {
  __shared__ ushort tile[32][772];
  int bb = blockIdx.y;
  int l0 = blockIdx.x << 5;
  int wv = threadIdx.x >> 6, lane = threadIdx.x & 63;
  const float4* w14 = (const float4*)w1;
  const float4* b14 = (const float4*)b1;
  const float4* w24 = (const float4*)w2;
  const float4* b24 = (const float4*)b2;
  float4 W1[3], B1[3], W2[3], B2[3];
#pragma unroll
  for (int m = 0; m < 3; ++m) {
    W1[m] = w14[lane + 64 * m]; B1[m] = b14[lane + 64 * m];
    W2[m] = w24[lane + 64 * m]; B2[m] = b24[lane + 64 * m];
  }
#pragma unroll
  for (int i = 0; i < 8; ++i) {
    int r = (wv << 3) + i;
    size_t rowi = (size_t)bb * LL + l0 + r;
    // LN2 stats over G row
    const u16x4* gr = (const u16x4*)(Gbf + rowi * HH);
    float gv[12];
    float s = 0.f, s2 = 0.f;
#pragma unroll
    for (int m = 0; m < 3; ++m) {
      u16x4 q = gr[lane + 64 * m];
#pragma unroll
      for (int j = 0; j < 4; ++j) {
        float f = bf2f(q[j]);
        gv[m * 4 + j] = f;
        s += f; s2 += f * f;
      }
    }
#pragma unroll
    for (int off = 32; off >= 1; off >>= 1) {
      s  += __shfl_xor(s, off);
      s2 += __shfl_xor(s2, off);
    }
    float mu2  = s * (1.f / HH);
    float var2 = s2 * (1.f / HH) - mu2 * mu2;
    float rs2  = rsqrtf(var2 + 1e-5f);
    // out = base + LN2(G); accumulate LN1 stats of out
    const float4* br = (const float4*)(base + rowi * HH);
    float4* orow = (float4*)(out + rowi * HH);
    float ov[12];
    float t1 = 0.f, t2 = 0.f;
#pragma unroll
    for (int m = 0; m < 3; ++m) {
      float4 bv = br[lane + 64 * m];
      float4 o;
      o.x = bv.x + (gv[m * 4 + 0] - mu2) * rs2 * W2[m].x + B2[m].x;
      o.y = bv.y + (gv[m * 4 + 1] - mu2) * rs2 * W2[m].y + B2[m].y;
      o.z = bv.z + (gv[m * 4 + 2] - mu2) * rs2 * W2[m].z + B2[m].z;
      o.w = bv.w + (gv[m * 4 + 3] - mu2) * rs2 * W2[m].w + B2[m].w;
      orow[lane + 64 * m] = o;
      ov[m * 4 + 0] = o.x; ov[m * 4 + 1] = o.y;
      ov[m * 4 + 2] = o.z; ov[m * 4 + 3] = o.w;
      t1 += o.x + o.y + o.z + o.w;
      t2 += o.x * o.x + o.y * o.y + o.z * o.z + o.w * o.w;
    }
#pragma unroll
    for (int off = 32; off >= 1; off >>= 1) {
      t1 += __shfl_xor(t1, off);
      t2 += __shfl_xor(t2, off);
    }
    float mu1  = t1 * (1.f / HH);
    float var1 = t2 * (1.f / HH) - mu1 * mu1;
    float rs1  = rsqrtf(var1 + 1e-5f);
    float mf   = (float)mask[rowi];
#pragma unroll
    for (int m = 0; m < 3; ++m) {
      u16x4 o;
      o.x = f2bf(((ov[m * 4 + 0] - mu1) * rs1 * W1[m].x + B1[m].x) * mf);
      o.y = f2bf(((ov[m * 4 + 1] - mu1) * rs1 * W1[m].y + B1[m].y) * mf);
      o.z = f2bf(((ov[m * 4 + 2] - mu1) * rs1 * W1[m].z + B1[m].z) * mf);
      o.w = f2bf(((ov[m * 4 + 3] - mu1) * rs1 * W1[m].w + B1[m].w) * mf);
      *(u16x4*)&tile[r][(lane + 64 * m) << 2] = o;
    }
  }
  __syncthreads();
#pragma unroll
  for (int it = 0; it < 3; ++it) {
    int h = it * 256 + threadIdx.x;
    ushort* dst = U + (((size_t)bb * HH + h) << 9) + l0;
#pragma unroll
    for (int c = 0; c < 4; ++c) {
      bf16x8 o;
#pragma unroll
      for (int j = 0; j < 8; ++j) o[j] = (short)tile[c * 8 + j][h];
      *(bf16x8*)(dst + (c << 3)) = o;
    }
  }
}

// ---------------------------------------------------------------------------
// Final: out = base + LN2(Gbf)   (last layer, no next LN1)
// ---------------------------------------------------------------------------
__global__ __launch_bounds__(256) void ln_res_kernel(
    const ushort* __restrict__ Gbf, const float* __restrict__ w,
    const float* __restrict__ b, const float* __restrict__ base,
    float* __restrict__ out) {
  int wv = threadIdx.x >> 6, lane = threadIdx.x & 63;
  size_t r = (size_t)blockIdx.x * 4 + wv;
  const u16x4* gr = (const u16x4*)(Gbf + r * HH);
  float gv[12];
  float s = 0.f, s2 = 0.f;
#pragma unroll
  for (int m = 0; m < 3; ++m) {
    u16x4 q = gr[lane + 64 * m];
#pragma unroll
    for (int j = 0; j < 4; ++j) {
      float f = bf2f(q[j]);
      gv[m * 4 + j] = f;
      s += f; s2 += f * f;
    }
  }
#pragma unroll
  for (int off = 32; off >= 1; off >>= 1) {
    s  += __shfl_xor(s, off);
    s2 += __shfl_xor(s2, off);
  }
  float mu  = s * (1.f / HH);
  float var = s2 * (1.f / HH) - mu * mu;
  float rs  = rsqrtf(var + 1e-5f);
  const float4* w4 = (const float4*)w;
  const float4* b4 = (const float4*)b;
  const float4* br = (const float4*)(base + r * HH);
  float4* xr = (float4*)(out + r * HH);
#pragma unroll
  for (int m = 0; m < 3; ++m) {
    float4 ww = w4[lane + 64 * m], bb = b4[lane + 64 * m];
    float4 xv = br[lane + 64 * m];
    xv.x += (gv[m * 4 + 0] - mu) * rs * ww.x + bb.x;
    xv.y += (gv[m * 4 + 1] - mu) * rs * ww.y + bb.y;
    xv.z += (gv[m * 4 + 2] - mu) * rs * ww.z + bb.z;
    xv.w += (gv[m * 4 + 3] - mu) * rs * ww.w + bb.w;
    xr[lane + 64 * m] = xv;
  }
}

// ---------------------------------------------------------------------------
// MFMA Toeplitz conv + D*u + gelu.  One wg per h.  Output bf16 [B,H,L].
// ---------------------------------------------------------------------------
__global__ __launch_bounds__(256) void conv_mfma_kernel(
    const ushort* __restrict__ Ubf, const ushort* __restrict__ rev,
    const float* __restrict__ Dv, ushort* __restrict__ Cbf) {
  __shared__ ushort Ulds[32 * 512];    // 32 KB
  __shared__ ushort Ktab[8 * 1048];    // 16.4 KB
  int tid = threadIdx.x;
  int w = tid >> 6, lane = tid & 63;
  int h = blockIdx.x;

#pragma unroll
  for (int it = 0; it < 8; ++it) {
    int G = it * 256 + tid;
    int b = G >> 6, cg = G & 63;
    gload16(Ubf + (((size_t)b * HH + h) << 9) + ((cg ^ (b & 7)) << 3),
            (char*)Ulds + (size_t)(it * 256 + (tid & 0xFFC0)) * 16);
  }
  const ushort* revh = rev + ((size_t)h << 10);
#pragma unroll
  for (int it = 0; it < 5; ++it) {
    int G = it * 256 + tid;
    if (G < 1048) {
      int r = G / 131, pg = G - r * 131;
      int se = (pg << 3) - 17 - r;
      se = se < 0 ? 0 : (se > 1016 ? 1016 : se);
      gload16(revh + se, (char*)Ktab + (size_t)(it * 256 + (tid & 0xFFC0)) * 16);
    }
  }
  asm volatile("s_waitcnt vmcnt(0)" ::: "memory");
  __syncthreads();

  int cc = lane & 15, g = lane >> 4;
  int wt = w << 7;
  const char* kbase = (const char*)Ktab + (cc & 7) * 2096 - ((cc >> 3) << 4)
                      + (g << 4) + 2 * (528 - wt);
  const char* ubase = (const char*)Ulds;
  int usw = (cc & 7) << 4;

  f32x4 acc[8][2];
#pragma unroll
  for (int m = 0; m < 8; ++m)
#pragma unroll
    for (int n = 0; n < 2; ++n) acc[m][n] = (f32x4){0.f, 0.f, 0.f, 0.f};

  bf16x8 A[8];
#define LDA(slot, m, ks) A[slot] = *(const bf16x8*)(kbase - (m) * 32 + (ks) * 64)
  LDA(0, 0, 0); LDA(1, 1, 0); LDA(2, 2, 0); LDA(3, 3, 0);
  LDA(4, 4, 0); LDA(5, 5, 0); LDA(6, 6, 0); LDA(7, 7, 0);
#pragma unroll
  for (int ks = 0; ks < 16; ++ks) {
    if (ks > 0) {
      LDA((0 - 2 * ks) & 7, 0, ks);
      LDA((1 - 2 * ks) & 7, 1, ks);
    }
    int ub = ((ks << 6) + (g << 4)) ^ usw;
    bf16x8 B0 = *(const bf16x8*)(ubase + cc * 1024 + ub);
    bf16x8 B1 = *(const bf16x8*)(ubase + (16 + cc) * 1024 + ub);
#pragma unroll
    for (int m = 0; m < 8; ++m) {
      acc[m][0] = __builtin_amdgcn_mfma_f32_16x16x32_bf16(
          A[(m - 2 * ks) & 7], B0, acc[m][0], 0, 0, 0);
      acc[m][1] = __builtin_amdgcn_mfma_f32_16x16x32_bf16(
          A[(m - 2 * ks) & 7], B1, acc[m][1], 0, 0, 0);
    }
  }
#undef LDA

  float dh = Dv[h];
  const float c1 = 2.3021181306612f, c3 = 0.1029392186f;
#pragma unroll
  for (int n = 0; n < 2; ++n) {
    int b = (n << 4) + cc;
    const char* up = (const char*)Ulds + b * 1024;
#pragma unroll
    for (int m = 0; m < 8; ++m) {
      int t0 = wt + (m << 4) + (g << 2);
      u16x4 uq = *(const u16x4*)(up + ((t0 << 1) ^ usw));
      u16x4 o;
#pragma unroll
      for (int r = 0; r < 4; ++r) {
        float y = acc[m][n][r] + dh * bf2f(uq[r]);
        float e = __builtin_amdgcn_exp2f(-(c1 * y + c3 * y * y * y));
        float gg = y * __builtin_amdgcn_rcpf(1.f + e);
        o[r] = f2bf(gg);
      }
      *(u16x4*)(Cbf + (((size_t)b * HH + h) << 9) + t0) = o;
    }
  }
}

// ---------------------------------------------------------------------------
// bf16 [B,H,L] -> bf16 [B,L,H]
// ---------------------------------------------------------------------------
__global__ __launch_bounds__(256) void t2bf_bf_kernel(
    const ushort* __restrict__ C, ushort* __restrict__ Y) {
  __shared__ ushort tile[32][34];
  int b = blockIdx.z;
  int h0 = blockIdx.x << 5, l0 = blockIdx.y << 5;
  int tx = threadIdx.x, ty = threadIdx.y;
#pragma unroll
  for (int k = 0; k < 4; ++k)
    tile[ty + 8 * k][tx] = C[(((size_t)b * HH + h0 + ty + 8 * k) << 9) + l0 + tx];
  __syncthreads();
#pragma unroll
  for (int k = 0; k < 4; ++k)
    Y[((size_t)b * LL + l0 + ty + 8 * k) * HH + h0 + tx] = tile[tx][ty + 8 * k];
}

// ---------------------------------------------------------------------------
// bf16 MFMA GEMM: Gbf[b,l,o] = bf16( Ybf[b,l,:]*Wbf[o,:] + bias )
// ---------------------------------------------------------------------------
__global__ __launch_bounds__(256) void gemm_kernel(
    const ushort* __restrict__ Ybf, const ushort* __restrict__ Wbf,
    const float* __restrict__ bias, ushort* __restrict__ Gb) {
  __shared__ ushort As[128 * 64];
  __shared__ ushort Bs[128 * 64];
  int tid = threadIdx.x;
  int wv = tid >> 6, lane = tid & 63;
  int wm = wv >> 1, wn = wv & 1;
  int b  = blockIdx.y >> 2;
  int l0 = (blockIdx.y & 3) << 7;
  int o0 = blockIdx.x << 7;

  int swz8 = (((lane & 7) ^ (lane >> 3)) << 3);
  int rsub = (lane >> 3);
  size_t arow0 = (size_t)(b * LL + l0 + wv * 32 + rsub) * HH;
  size_t brow0 = (size_t)(o0 + wv * 32 + rsub) * HH;
  char* Adst = (char*)As + wv * 4096;
  char* Bdst = (char*)Bs + wv * 4096;

  f32x4 acc[4][4];
#pragma unroll
  for (int i = 0; i < 4; ++i)
#pragma unroll
    for (int j = 0; j < 4; ++j) acc[i][j] = (f32x4){0.f, 0.f, 0.f, 0.f};

  for (int kt = 0; kt < HH / 64; ++kt) {
    int h0 = kt * 64;
#pragma unroll
    for (int i = 0; i < 4; ++i) {
      gload16(Ybf + arow0 + (size_t)i * 8 * HH + h0 + swz8, Adst + i * 1024);
      gload16(Wbf + brow0 + (size_t)i * 8 * HH + h0 + swz8, Bdst + i * 1024);
    }
    __syncthreads();

    bf16x8 af[4][2], bfr[4][2];
#pragma unroll
    for (int mi = 0; mi < 4; ++mi) {
      int m = wm * 64 + mi * 16 + (lane & 15);
#pragma unroll
      for (int kk = 0; kk < 2; ++kk) {
        int off = m * 128 + ((((lane >> 4) << 4) + (kk << 6)) ^ ((lane & 7) << 4));
        af[mi][kk] = *(const bf16x8*)((const char*)As + off);
      }
    }
#pragma unroll
    for (int ni = 0; ni < 4; ++ni) {
      int n = wn * 64 + ni * 16 + (lane & 15);
#pragma unroll
      for (int kk = 0; kk < 2; ++kk) {
        int off = n * 128 + ((((lane >> 4) << 4) + (kk << 6)) ^ ((lane & 7) << 4));
        bfr[ni][kk] = *(const bf16x8*)((const char*)Bs + off);
      }
    }
#pragma unroll
    for (int kk = 0; kk < 2; ++kk)
#pragma unroll
      for (int mi = 0; mi < 4; ++mi)
#pragma unroll
        for (int ni = 0; ni < 4; ++ni)
          acc[mi][ni] = __builtin_amdgcn_mfma_f32_16x16x32_bf16(
              af[mi][kk], bfr[ni][kk], acc[mi][ni], 0, 0, 0);
    __syncthreads();
  }

#pragma unroll
  for (int ni = 0; ni < 4; ++ni) {
    int n_g = o0 + wn * 64 + ni * 16 + (lane & 15);
    float bv = bias[n_g];
#pragma unroll
    for (int mi = 0; mi < 4; ++mi) {
      int m_g = l0 + wm * 64 + mi * 16 + ((lane >> 4) << 2);
      ushort* gp = Gb + ((size_t)b * LL + m_g) * HH + n_g;
#pragma unroll
      for (int j = 0; j < 4; ++j)
        gp[(size_t)j * HH] = f2bf(acc[mi][ni][j] + bv);
    }
  }
}

// ---------------------------------------------------------------------------
extern "C" void kernel_launch(void* const* d_in, const int* in_sizes, int n_in,
                              void* d_out, int out_size, void* d_ws, size_t ws_size,
                              hipStream_t stream) {
  const float* x      = (const float*)d_in[0];
  const int*   mask   = (const int*)d_in[1];
  const float* ln1_w  = (const float*)d_in[2];
  const float* ln1_b  = (const float*)d_in[3];
  const float* log_dt = (const float*)d_in[4];
  const float* A_re   = (const float*)d_in[5];
  const float* A_im   = (const float*)d_in[6];
  const float* C_re   = (const float*)d_in[7];
  const float* C_im   = (const float*)d_in[8];
  const float* Dv     = (const float*)d_in[9];
  const float* Wout   = (const float*)d_in[10];
  const float* bout   = (const float*)d_in[11];
  const float* ln2_w  = (const float*)d_in[12];
  const float* ln2_b  = (const float*)d_in[13];
  float* out = (float*)d_out;

  // ws: rev | Ubf (reused as Ybf) | Cbf | Wbf | Gbf
  ushort* rev  = (ushort*)d_ws;                               // NL*H*1024
  ushort* Ubf  = rev + (size_t)NLAYERS * HH * 1024;           // B*H*L
  ushort* Cbf  = Ubf + (size_t)BB * HH * LL;                  // B*H*L
  ushort* Wbf  = Cbf + (size_t)BB * HH * LL;                  // NL*H*H
  ushort* Gbf  = Wbf + (size_t)NLAYERS * HH * HH;             // B*L*H
  ushort* Ybf  = Ubf;   // safe reuse: conv consumed Ubf before t2bf writes it

  compute_k_kernel<<<NLAYERS * HH / 2, 256, 0, stream>>>(
      log_dt, A_re, A_im, C_re, C_im, rev);
  wcast_kernel<<<(NLAYERS * HH * HH) / (256 * 8), 256, 0, stream>>>(Wout, Wbf);

  ln_t_kernel<<<dim3(LL / 32, BB), 256, 0, stream>>>(
      x, ln1_w, ln1_b, mask, Ubf);

  for (int il = 0; il < NLAYERS; ++il) {
    const float* base = (il == 0) ? x : out;
    conv_mfma_kernel<<<HH, 256, 0, stream>>>(
        Ubf, rev + (size_t)il * HH * 1024, Dv + il * HH, Cbf);
    t2bf_bf_kernel<<<dim3(HH / 32, LL / 32, BB), dim3(32, 8), 0, stream>>>(Cbf, Ybf);
    gemm_kernel<<<dim3(HH / 128, BB * LL / 128), 256, 0, stream>>>(
        Ybf, Wbf + (size_t)il * HH * HH, bout + il * HH, Gbf);
    if (il < NLAYERS - 1) {
      res_lnt_kernel<<<dim3(LL / 32, BB), 256, 0, stream>>>(
          Gbf, ln2_w + il * HH, ln2_b + il * HH, base, out,
          mask, ln1_w + (il + 1) * HH, ln1_b + (il + 1) * HH, Ubf);
    } else {
      ln_res_kernel<<<BB * LL / 4, 256, 0, stream>>>(
          Gbf, ln2_w + il * HH, ln2_b + il * HH, base, out);
    }
  }
}